// Round 15
// baseline (5856.450 us; speedup 1.0000x reference)
//
#include <hip/hip_runtime.h>

typedef unsigned int uint;
typedef unsigned short ushort;
typedef unsigned long long ull;
typedef __attribute__((ext_vector_type(8))) short bf16x8;
typedef __attribute__((ext_vector_type(4))) float f32x4;

static constexpr int V_ = 32000, E_ = 256, H_ = 512, B_ = 16, S_ = 512, T_ = 128;
static constexpr int H2_ = 1024, G4_ = 2048, D4_ = 4096, KXI_ = 2304; // 256+1024+1024
static constexpr int DSTEPS = T_ - 1;  // 127
static constexpr int MD = 2048;        // padded rows for preds GEMM (2032 valid)
static constexpr int NWG_DEC = 256;
static constexpr float LOG2E = 1.4426950408889634f;
static constexpr int ASTR = 2312;      // AB padded row stride (ushorts)

#define DEVFN __device__ __forceinline__

DEVFN ushort f2bf(float f){ uint u = __builtin_bit_cast(uint, f); u += 0x7fffu + ((u>>16)&1u); return (ushort)(u>>16); }
DEVFN float bf2f(ushort h){ uint u = ((uint)h)<<16; return __builtin_bit_cast(float, u); }
DEVFN float fsig(float x){ float e = __builtin_amdgcn_exp2f(-LOG2E*x); return __builtin_amdgcn_rcpf(1.f+e); }
DEVFN float ftanh(float x){ x = fminf(15.f,fmaxf(-15.f,x)); float e = __builtin_amdgcn_exp2f(2.f*LOG2E*x); return (e-1.f)*__builtin_amdgcn_rcpf(e+1.f); }
DEVFN f32x4 mfma16(bf16x8 a, bf16x8 b, f32x4 c){ return __builtin_amdgcn_mfma_f32_16x16x32_bf16(a,b,c,0,0,0); }

// ---- coherent helpers: agent-scope relaxed atomics (sc1-only -> L3-served).
// NOT "sc0 sc1" system scope (HBM every access — the r5-7 regression).
// Register pre-issue of CACHED operands before sync windows is safe (adds no
// traffic); r11's regression was the replicated-WaH L2 pollution, not pre-issue.
struct ull2v{ ull x, y; };
DEVFN ull ald64(const void* p){ return __hip_atomic_load((const ull*)p, __ATOMIC_RELAXED, __HIP_MEMORY_SCOPE_AGENT); }
DEVFN uint ald32u(const uint* p){ return __hip_atomic_load(p, __ATOMIC_RELAXED, __HIP_MEMORY_SCOPE_AGENT); }
DEVFN float ald_f32(const float* p){ uint v = __hip_atomic_load((const uint*)p, __ATOMIC_RELAXED, __HIP_MEMORY_SCOPE_AGENT); return __builtin_bit_cast(float, v); }
DEVFN void ast32(float* p, float v){ __hip_atomic_store(p, v, __ATOMIC_RELAXED, __HIP_MEMORY_SCOPE_AGENT); }
DEVFN void ast16(ushort* p, ushort v){ __hip_atomic_store(p, v, __ATOMIC_RELAXED, __HIP_MEMORY_SCOPE_AGENT); }
DEVFN void astu(uint* p, uint v){ __hip_atomic_store(p, v, __ATOMIC_RELAXED, __HIP_MEMORY_SCOPE_AGENT); }

// group-local flag barrier (r10 proven)
DEVFN void lbar(uint* lflags, int grp, int mem, int tid, uint& rnd){
  __syncthreads();
  rnd++;
  if (tid==0) astu(lflags + grp*16 + mem, rnd);
  if (tid<16){
    while (ald32u(lflags + grp*16 + tid) < rnd) __builtin_amdgcn_s_sleep(1);
  }
  __syncthreads();
}

// zero flags + tagged buffers. Exact-match tags require zero init on EVERY call
// (graph replays) so stale tags from the previous call never satisfy a poll.
__global__ void k_init(uint* __restrict__ flags, uint* __restrict__ hgf, uint* __restrict__ hgb,
                       uint* __restrict__ hU, uint* __restrict__ ctxU){
  int i = blockIdx.x*256 + threadIdx.x;   // 32768 threads
  if (i < 1024) flags[i] = 0;
  if (i < 2*B_*H_){ hgf[i]=0u; hgb[i]=0u; }
  if (i < B_*H2_) hU[i] = 0u;
  if (i < 2*B_*H2_) ctxU[i] = 0u;
}

// ---------------- embedding gather ----------------
__global__ void k_embed(const int* __restrict__ src, const int* __restrict__ tgt,
                        const float* __restrict__ emb, ushort* __restrict__ Xb, ushort* __restrict__ DXb){
  int r = blockIdx.x, tid = threadIdx.x;
  if (r < S_*B_){
    int s = r>>4, b = r&15;
    int id = src[b*S_+s];
    Xb[(size_t)r*E_+tid] = f2bf(emb[(size_t)id*E_+tid]);
  } else {
    int r2 = r - S_*B_;
    int t = r2>>4, b = r2&15;
    int id = tgt[b*T_+t];
    DXb[(size_t)r2*E_+tid] = f2bf(emb[(size_t)id*E_+tid]);
  }
}

// encoder Wih convert: d: wg=d>>7, r=d&127, w=r>>4, jj=(r>>2)&3, g=r&3
// -> src row g*512 + wg*32 + w*4 + jj
__global__ void k_cvt_encw(const float* __restrict__ src, ushort* __restrict__ dst){
  int d = blockIdx.x;
  int wg = d>>7, r = d&127;
  int w = r>>4, jj=(r>>2)&3, g=r&3;
  int srow = g*H_ + wg*32 + w*4 + jj;
  for (int c = threadIdx.x; c < E_; c += 256)
    dst[(size_t)d*E_ + c] = f2bf(src[(size_t)srow*E_ + c]);
}

__global__ void k_bias_encp(const float* __restrict__ bih, const float* __restrict__ bhh, float* __restrict__ dst){
  int d = blockIdx.x*256 + threadIdx.x;
  int wg = d>>7, r = d&127;
  int w = r>>4, jj=(r>>2)&3, g=r&3;
  int srow = g*H_ + wg*32 + w*4 + jj;
  dst[d] = bih[srow]+bhh[srow];
}

// decoder Wd convert (256 WGs x 16 rows): dst row d: wg=d>>4, r=d&15,
// jj=r>>2, g=r&3 -> src row g*1024 + wg*4 + jj
__global__ void k_cvt_decw(const float* __restrict__ Wih_d, const float* __restrict__ Whh_d,
                           ushort* __restrict__ dst){
  int d = blockIdx.x;
  int wg = d>>4, r = d&15, jj = r>>2, g = r&3;
  int srow = g*H2_ + wg*4 + jj;
  for (int c = threadIdx.x; c < KXI_; c += 256){
    float v = (c < E_+H2_) ? Wih_d[(size_t)srow*(E_+H2_) + c] : Whh_d[(size_t)srow*H2_ + (c - (E_+H2_))];
    dst[(size_t)d*KXI_ + c] = f2bf(v);
  }
}

__global__ void k_bias_decp(const float* __restrict__ bih, const float* __restrict__ bhh, float* __restrict__ dst){
  int d = blockIdx.x*256 + threadIdx.x;
  int wg = d>>4, r = d&15, jj = r>>2, g = r&3;
  int srow = g*H2_ + wg*4 + jj;
  dst[d] = bih[srow]+bhh[srow];
}

__global__ void k_cvt_strided(const float* __restrict__ src, ushort* __restrict__ dst,
                              int cols, int sld, int soff, int dld, int doff){
  int r = blockIdx.x;
  for (int c = threadIdx.x; c < cols; c += 256)
    dst[(size_t)r*dld + doff + c] = f2bf(src[(size_t)r*sld + soff + c]);
}

__global__ void k_zero_t0(float* __restrict__ out){
  int i = blockIdx.x*256 + threadIdx.x;
  if (i < B_*V_){ int b = i / V_, v = i - b*V_; out[(size_t)b*T_*V_ + v] = 0.f; }
}

// ---------------- 128x128-tile bf16 MFMA GEMM ----------------
template<int MODE>
__global__ __launch_bounds__(256) void gemm128(const ushort* __restrict__ A, const ushort* __restrict__ Bm,
    const float* __restrict__ bias, void* __restrict__ outp, int M, int N, int K, int Mvalid){
  __shared__ __align__(16) ushort As[128*32];
  __shared__ __align__(16) ushort Bs[128*32];
  int tid = threadIdx.x;
  int wave = tid>>6, lane = tid&63;
  int m0 = blockIdx.y*128, n0 = blockIdx.x*128;
  int wm = wave>>1, wn = wave&1;
  int col = lane&15, rg = lane>>4;
  f32x4 acc[4][4];
  #pragma unroll
  for (int i=0;i<4;i++)
    #pragma unroll
    for (int j=0;j<4;j++) acc[i][j] = {0.f,0.f,0.f,0.f};
  for (int k0=0;k0<K;k0+=32){
    __syncthreads();
    #pragma unroll
    for (int j=0;j<2;j++){
      int li = j*256+tid;
      int row = li>>2, ko = (li&3)*8;
      *(bf16x8*)(As + li*8) = *(const bf16x8*)(A + (size_t)(m0+row)*K + k0 + ko);
      *(bf16x8*)(Bs + li*8) = *(const bf16x8*)(Bm + (size_t)(n0+row)*K + k0 + ko);
    }
    __syncthreads();
    bf16x8 af[4], bfr[4];
    #pragma unroll
    for (int f=0;f<4;f++){
      af[f]  = *(const bf16x8*)(As + (wm*64+f*16+col)*32 + rg*8);
      bfr[f] = *(const bf16x8*)(Bs + (wn*64+f*16+col)*32 + rg*8);
    }
    #pragma unroll
    for (int fm=0;fm<4;fm++)
      #pragma unroll
      for (int fn=0;fn<4;fn++)
        acc[fm][fn] = mfma16(af[fm], bfr[fn], acc[fm][fn]);
  }
  #pragma unroll
  for (int fm=0;fm<4;fm++){
    int mrow = m0 + wm*64 + fm*16 + rg*4;
    #pragma unroll
    for (int fn=0;fn<4;fn++){
      int gcol = n0 + wn*64 + fn*16 + col;
      float bv = bias ? bias[gcol] : 0.f;
      #pragma unroll
      for (int i=0;i<4;i++){
        float v = acc[fm][fn][i] + bv;
        int grow = mrow + i;
        if (MODE==0) ((float*)outp)[(size_t)grow*N + gcol] = v;
        else if (MODE==1) ((ushort*)outp)[(size_t)grow*N + gcol] = f2bf(v);
        else if (MODE==3) ((ushort*)outp)[(size_t)(grow>>4)*(16*2048) + gcol*16 + (grow&15)] = f2bf(v);
        else { if (grow < Mvalid){ int b = grow&15, t = grow>>4;
               ((float*)outp)[(size_t)b*T_*V_ + (size_t)(t+1)*V_ + gcol] = v; } }
      }
    }
  }
}

// ---------------- persistent bidirectional encoder: 16 WGs/dir x 512 thr ----------------
// h exchange via in-band tags (r14). Xg load hoisted above the h-poll so its
// latency hides under the poll window.
__global__ __launch_bounds__(512) void k_enc_persist(
    const ushort* __restrict__ Xgf, const ushort* __restrict__ Xgb,
    const float* __restrict__ Whhf, const float* __restrict__ Whhb,
    ushort* __restrict__ enc, ushort* __restrict__ enct,
    uint* __restrict__ hbuf1, float* __restrict__ cbuf0,
    uint* __restrict__ hgf, uint* __restrict__ hgb){
  const int dir = blockIdx.x >> 4;
  const int wg  = blockIdx.x & 15;
  const ushort* Xg = dir ? Xgb : Xgf;
  const float* Whh = dir ? Whhb : Whhf;
  uint* hg = dir ? hgb : hgf;
  __shared__ __align__(16) ushort Wlds[128*512];   // 128 KiB, XOR-swizzled
  __shared__ __align__(16) ushort hls[16*512];     // 16 KiB staged h, XOR-swizzled
  int tid = threadIdx.x;
  for (int it=0; it<32; ++it){
    int r = it*4 + (tid>>7), ct = tid&127;
    int w_ = r>>4, jj=(r>>2)&3, g=r&3;
    int srow = g*H_ + wg*32 + w_*4 + jj;
    float4 v = *(const float4*)(Whh + (size_t)srow*H_ + ct*4);
    ushort4 o; o.x=f2bf(v.x); o.y=f2bf(v.y); o.z=f2bf(v.z); o.w=f2bf(v.w);
    int byte = (r*1024 + ct*8) ^ ((r&7)<<4);
    *(ushort4*)((char*)Wlds + byte) = o;
  }
  int w = tid>>6, lane = tid&63, colL = lane&15, rg = lane>>4;
  int gg = colL&3;
  float cst[4];
  #pragma unroll
  for (int i=0;i<4;i++) cst[i]=0.f;
  __syncthreads();
  for (int t=0;t<S_;++t){
    int pos = dir ? (S_-1-t) : t;
    const uint* hsrcU = hg + (t&1)*B_*H_;
    // pre-issue Xg load (independent of h) — hides under the poll
    int colg = wg*128 + w*16 + colL;
    ushort4 xv = *(const ushort4*)(Xg + ((size_t)pos*2048 + colg)*16 + rg*4);
    // tag-poll h_t: want tag == t (t=0: zeros, tag 0)
    uint uu[16];
    for(;;){
      #pragma unroll
      for (int k2=0;k2<2;k2++){
        int idx = tid + k2*512;
        const uint* p = hsrcU + (idx>>6)*H_ + (idx&63)*8;
        #pragma unroll
        for (int j=0;j<4;j++){
          ull v = ald64(p + j*2);
          uu[k2*8+j*2] = (uint)v; uu[k2*8+j*2+1] = (uint)(v>>32);
        }
      }
      bool ok = true;
      #pragma unroll
      for (int i2=0;i2<16;i2++) ok &= ((uu[i2]>>16) == (uint)t);
      if (ok) break;
      __builtin_amdgcn_s_sleep(1);
    }
    f32x4 acc;
    acc[0]=bf2f(xv.x); acc[1]=bf2f(xv.y); acc[2]=bf2f(xv.z); acc[3]=bf2f(xv.w);
    #pragma unroll
    for (int k2=0;k2<2;k2++){
      int idx = tid + k2*512;
      int byte = ((idx>>6)*1024 + (idx&63)*16) ^ (((idx>>6)&7)<<4);
      ushort tmp[8];
      #pragma unroll
      for (int j=0;j<8;j++) tmp[j] = (ushort)uu[k2*8+j];
      *(bf16x8*)((char*)hls + byte) = *(bf16x8*)tmp;
    }
    __syncthreads();
    int rowb = w*16 + colL;
    int base = rowb*1024 + rg*16, xm = (rowb&7)<<4;
    int hbase = colL*1024 + rg*16, hxm = (colL&7)<<4;
    #pragma unroll
    for (int kt=0;kt<16;kt++){
      bf16x8 afv = *(const bf16x8*)((const char*)hls + ((hbase + kt*64) ^ hxm));
      bf16x8 bfv = *(const bf16x8*)((const char*)Wlds + ((base + kt*64) ^ xm));
      acc = mfma16(afv, bfv, acc);
    }
    uint* hdstU = hg + ((t+1)&1)*B_*H_;
    #pragma unroll
    for (int i=0;i<4;i++){
      float v0 = acc[i];
      float v1 = __shfl_xor(v0, 1);
      float v2 = __shfl_xor(v0, 2);
      float v3 = __shfl_xor(v1, 2);
      float zi = gg==0?v0: gg==1?v1: gg==2?v2: v3;
      float zf = (gg^1)==0?v0: (gg^1)==1?v1: (gg^1)==2?v2: v3;
      float zg = (gg^2)==0?v0: (gg^2)==1?v1: (gg^2)==2?v2: v3;
      float zo = (gg^3)==0?v0: (gg^3)==1?v1: (gg^3)==2?v2: v3;
      float cc = fsig(zf)*cst[i] + fsig(zi)*ftanh(zg);
      cst[i] = cc;
      float h = fsig(zo)*ftanh(cc);
      if (gg==0){
        int j = wg*32 + w*4 + (colL>>2);
        int b = rg*4+i;
        ushort hb = f2bf(h);
        enc[((size_t)b*S_ + pos)*H2_ + dir*H_ + j] = hb;
        enct[((size_t)b*H2_ + dir*H_ + j)*S_ + pos] = hb;
        astu(&hdstU[b*H_ + j], (uint)hb | ((uint)(t+1)<<16));
        if (t==S_-1){
          hbuf1[b*H2_ + dir*H_ + j] = (uint)hb;  // decoder h0, tag 0
          cbuf0[b*H2_ + dir*H_ + j] = cc;        // decoder c0
        }
      }
    }
    __syncthreads();   // protect hls reuse across steps
  }
}

// ---------------- persistent decoder: 256 WGs x 512 threads, tag-synced ----------------
// r14 structure + per-phase constant-operand pre-issue (P/ENCT/Wd/WaH are
// L2-cached; loads issued before each sync window so latency hides under the
// poll). D's two tag-polls merged into one loop (halves serial poll RTs).
__global__ __launch_bounds__(512) void k_dec(
    const float* __restrict__ P, const ushort* __restrict__ WaH,
    const ushort* __restrict__ Wd, const float* __restrict__ bsd,
    const ushort* __restrict__ enct, const ushort* __restrict__ DXb,
    const float* __restrict__ cbuf0, uint* __restrict__ hU,
    uint* __restrict__ ctxU, float* __restrict__ qbuf,
    float* __restrict__ scores, ushort* __restrict__ hsd,
    uint* __restrict__ flags){
  __shared__ __align__(16) ushort AB[16*ASTR];   // 74KB phase-D xi stage
  __shared__ __align__(16) float pr[8*256];
  __shared__ float redz[256];
  __shared__ float qls[1024];
  __shared__ float wls[512];
  __shared__ float part[512];
  __shared__ float red[16];
  __shared__ float cst[64];
  uint* lflags = flags + 256;
  uint* qf     = flags + 768;   // 64 producer q-flags
  int wgid = blockIdx.x, tid = threadIdx.x;
  int w = tid>>6, lane = tid&63, colL = lane&15, rg = lane>>4;
  int b = wgid>>4, wc = wgid&15;
  uint rnd = 0;
  if (tid < 64){
    int jj = tid>>4, b4 = tid&15;
    cst[tid] = cbuf0[b4*H2_ + wgid*4 + jj];
  }
  for (int st=0; st<DSTEPS; ++st){
    const uint* hprevU = hU + ((st+1)&1)*B_*H2_;
    uint* cslot = ctxU + (st&1)*B_*H2_;
    const uint wantH = (uint)st;
    const uint wantC = (uint)(st+1);
    float* qslot = qbuf + (st&1)*B_*H2_;
    // ---- phase A: q = h_{t-1} @ WaH^T (WGs 64..127); WaH pre-issued, h tag-poll ----
    if (wgid >= 64 && wgid < 128){
      int n0 = (wgid-64)*16;
      const ushort* Bp = WaH + (size_t)(n0+colL)*H2_ + w*128 + rg*8;
      bf16x8 bwa[4];
      #pragma unroll
      for (int kt=0;kt<4;kt++) bwa[kt] = *(const bf16x8*)(Bp + kt*32);
      const uint* hp = hprevU + colL*H2_ + w*128 + rg*8;
      uint uu[32];
      for(;;){
        #pragma unroll
        for (int kt=0;kt<4;kt++)
          #pragma unroll
          for (int j=0;j<4;j++){
            ull v = ald64(hp + kt*32 + j*2);
            uu[kt*8+j*2] = (uint)v; uu[kt*8+j*2+1] = (uint)(v>>32);
          }
        bool ok = true;
        #pragma unroll
        for (int i2=0;i2<32;i2++) ok &= ((uu[i2]>>16) == wantH);
        if (ok) break;
        __builtin_amdgcn_s_sleep(1);
      }
      f32x4 acc = {0.f,0.f,0.f,0.f};
      #pragma unroll
      for (int kt=0;kt<4;kt++){
        ushort tmp[8];
        #pragma unroll
        for (int j=0;j<8;j++) tmp[j] = (ushort)uu[kt*8+j];
        acc = mfma16(*(bf16x8*)tmp, bwa[kt], acc);
      }
      *(f32x4*)&pr[w*256 + lane*4] = acc;
      __syncthreads();
      if (tid < 256){
        float s = pr[tid];
        #pragma unroll
        for (int w8=1;w8<8;w8++) s += pr[w8*256 + tid];
        int l = tid>>2, i = tid&3;
        ast32(&qslot[(size_t)((l>>4)*4 + i)*H2_ + n0 + (l&15)], s);
      }
      __syncthreads();                       // drains q stores (vmcnt)
      if (tid==0) astu(qf + (wgid-64), wantC);
    }
    // ---- pre-issue P (L2-cached, independent of q) then poll q-flags ----
    f32x4 pv[16];
    {
      int rbase = b*S_ + wc*32 + w*4;
      #pragma unroll
      for (int rr=0;rr<4;rr++){
        const f32x4* Pr = (const f32x4*)(P + (size_t)(rbase+rr)*H2_) + lane*4;
        #pragma unroll
        for (int u=0;u<4;u++) pv[rr*4+u] = Pr[u];
      }
    }
    if (tid < 64){
      while (ald32u(qf + tid) < wantC) __builtin_amdgcn_s_sleep(1);
    }
    __syncthreads();
    // ---- phase B: scores = sum_k tanh(P + q) ----
    {
      ull q2 = ald64((const ull*)(qslot + (size_t)b*H2_) + tid);
      *(ull*)&qls[tid*2] = q2;
      __syncthreads();
      f32x4 qv[4];
      #pragma unroll
      for (int u=0;u<4;u++) qv[u] = *(const f32x4*)&qls[lane*16 + u*4];
      int rbase = b*S_ + wc*32 + w*4;
      #pragma unroll
      for (int rr=0;rr<4;rr++){
        float s = 0.f;
        #pragma unroll
        for (int u=0;u<4;u++){
          f32x4 p4 = pv[rr*4+u];
          s += ftanh(p4[0]+qv[u][0])+ftanh(p4[1]+qv[u][1])+ftanh(p4[2]+qv[u][2])+ftanh(p4[3]+qv[u][3]);
        }
        #pragma unroll
        for (int o=32;o;o>>=1) s += __shfl_xor(s,o);
        if (lane==0) ast32(&scores[rbase+rr], s);
      }
    }
    // ---- pre-issue ENCT (independent of scores) then group-local lbar ----
    bf16x8 ev[8];
    {
      int c = wc*64 + (tid&63), sseg = tid>>6;
      const ushort* ep = enct + ((size_t)b*H2_ + c)*S_ + sseg*64;
      #pragma unroll
      for (int u=0;u<8;u++) ev[u] = *(const bf16x8*)(ep + u*8);
    }
    lbar(lflags, b, wc, tid, rnd);
    // ---- phase C: softmax (replicated per b) + ctx; ctx TAGGED ----
    {
      float sc = ald_f32(scores + b*S_ + tid);
      float m = sc;
      #pragma unroll
      for (int o=32;o;o>>=1) m = fmaxf(m, __shfl_xor(m,o));
      if (lane==0) red[w] = m;
      __syncthreads();
      m = red[0];
      #pragma unroll
      for (int k2=1;k2<8;k2++) m = fmaxf(m, red[k2]);
      float e = __builtin_amdgcn_exp2f((sc - m)*LOG2E);
      float ss = e;
      #pragma unroll
      for (int o=32;o;o>>=1) ss += __shfl_xor(ss,o);
      if (lane==0) red[8+w] = ss;
      __syncthreads();
      float tot = red[8];
      #pragma unroll
      for (int k2=9;k2<16;k2++) tot += red[k2];
      wls[tid] = e * __builtin_amdgcn_rcpf(tot);
      __syncthreads();
      int sseg = tid>>6;
      float a = 0.f;
      #pragma unroll
      for (int u=0;u<8;u++){
        #pragma unroll
        for (int j=0;j<8;j++) a += wls[sseg*64 + u*8 + j] * bf2f((ushort)ev[u][j]);
      }
      part[tid] = a;
      __syncthreads();
      if (tid < 64){
        float s = part[tid];
        #pragma unroll
        for (int g2=1;g2<8;g2++) s += part[g2*64 + tid];
        astu(&cslot[b*H2_ + wc*64 + tid], (uint)f2bf(s) | (wantC<<16));
      }
    }
    // ---- phase D: pre-issue Wd, merged ctx+h tag-poll, stage, MFMA, cell ----
    {
      { int b3 = tid>>5, seg = tid&31;
        *(bf16x8*)&AB[b3*ASTR + seg*8] = *(const bf16x8*)(DXb + (size_t)(st*16+b3)*E_ + seg*8); }
      bf16x8 bw[9];
      {
        int row0 = wgid*16;
        const ushort* Bp = Wd + (size_t)(row0+colL)*KXI_ + w*288 + rg*8;
        #pragma unroll
        for (int kt=0;kt<9;kt++) bw[kt] = *(const bf16x8*)(Bp + kt*32);
      }
      // merged ctx+h tag-poll (one loop, both buffers in flight)
      uint uc[32], uh[32];
      for(;;){
        #pragma unroll
        for (int k2=0;k2<4;k2++){
          int idx = tid + k2*512;
          const uint* pc = cslot  + (idx>>7)*H2_ + (idx&127)*8;
          const uint* ph = hprevU + (idx>>7)*H2_ + (idx&127)*8;
          #pragma unroll
          for (int j=0;j<4;j++){
            ull vc = ald64(pc + j*2);
            ull vh = ald64(ph + j*2);
            uc[k2*8+j*2] = (uint)vc; uc[k2*8+j*2+1] = (uint)(vc>>32);
            uh[k2*8+j*2] = (uint)vh; uh[k2*8+j*2+1] = (uint)(vh>>32);
          }
        }
        bool ok = true;
        #pragma unroll
        for (int i2=0;i2<32;i2++) ok &= ((uc[i2]>>16) == wantC) && ((uh[i2]>>16) == wantH);
        if (ok) break;
        __builtin_amdgcn_s_sleep(1);
      }
      #pragma unroll
      for (int k2=0;k2<4;k2++){
        int idx = tid + k2*512;
        ushort tc[8], th[8];
        #pragma unroll
        for (int j=0;j<8;j++){ tc[j] = (ushort)uc[k2*8+j]; th[j] = (ushort)uh[k2*8+j]; }
        *(bf16x8*)&AB[(idx>>7)*ASTR + 256  + (idx&127)*8] = *(bf16x8*)tc;
        *(bf16x8*)&AB[(idx>>7)*ASTR + 1280 + (idx&127)*8] = *(bf16x8*)th;
      }
      __syncthreads();
      int row0 = wgid*16;
      f32x4 acc = {0.f,0.f,0.f,0.f};
      const ushort* Apb = &AB[colL*ASTR + w*288 + rg*8];
      #pragma unroll
      for (int kt=0;kt<9;kt++)
        acc = mfma16(*(const bf16x8*)(Apb + kt*32), bw[kt], acc);
      *(f32x4*)&pr[w*256 + lane*4] = acc;
      __syncthreads();
      if (tid < 256){
        float s = bsd[row0 + ((tid>>2)&15)];
        #pragma unroll
        for (int w8=0;w8<8;w8++) s += pr[w8*256 + tid];
        redz[tid] = s;
      }
      __syncthreads();
      if (tid < 64){
        int jj = tid>>4, b4 = tid&15, rgc = b4>>2, ic = b4&3;
        float zi = redz[((jj*4+0) + 16*rgc)*4 + ic];
        float zf = redz[((jj*4+1) + 16*rgc)*4 + ic];
        float zg = redz[((jj*4+2) + 16*rgc)*4 + ic];
        float zo = redz[((jj*4+3) + 16*rgc)*4 + ic];
        float cc2 = fsig(zf)*cst[tid] + fsig(zi)*ftanh(zg);
        cst[tid] = cc2;
        float h = fsig(zo)*ftanh(cc2);
        ushort hb = f2bf(h);
        int j = wgid*4 + jj;
        astu(&hU[(st&1)*B_*H2_ + b4*H2_ + j], (uint)hb | ((uint)(st+1)<<16));
        hsd[((size_t)st*B_ + b4)*H2_ + j] = hb;
      }
      __syncthreads();
    }
  }
}

extern "C" void kernel_launch(void* const* d_in, const int* in_sizes, int n_in,
                              void* d_out, int out_size, void* d_ws, size_t ws_size,
                              hipStream_t stream) {
  const int* src   = (const int*)d_in[0];
  const int* tgt   = (const int*)d_in[1];
  const float* emb   = (const float*)d_in[2];
  const float* Wih_f = (const float*)d_in[3];
  const float* Whh_f = (const float*)d_in[4];
  const float* bih_f = (const float*)d_in[5];
  const float* bhh_f = (const float*)d_in[6];
  const float* Wih_b = (const float*)d_in[7];
  const float* Whh_b = (const float*)d_in[8];
  const float* bih_b = (const float*)d_in[9];
  const float* bhh_b = (const float*)d_in[10];
  const float* Wih_d = (const float*)d_in[11];
  const float* Whh_d = (const float*)d_in[12];
  const float* bih_d = (const float*)d_in[13];
  const float* bhh_d = (const float*)d_in[14];
  const float* Wa    = (const float*)d_in[15];
  const float* ba    = (const float*)d_in[16];
  const float* Wo    = (const float*)d_in[17];
  const float* bo    = (const float*)d_in[18];
  float* out = (float*)d_out;
  (void)in_sizes; (void)n_in; (void)out_size; (void)ws_size;

  char* ws = (char*)d_ws;
  size_t off = 0;
  auto alloc = [&](size_t bytes)->char*{ char* p = ws + off; off += (bytes + 255) & ~(size_t)255; return p; };
  ushort* Xb     = (ushort*)alloc((size_t)S_*B_*E_*2);
  ushort* DXb    = (ushort*)alloc((size_t)DSTEPS*B_*E_*2);
  ushort* Wihf_p = (ushort*)alloc((size_t)G4_*E_*2);
  ushort* Wihb_p = (ushort*)alloc((size_t)G4_*E_*2);
  float*  bsf    = (float*)alloc(G4_*4);
  float*  bsb    = (float*)alloc(G4_*4);
  ushort* ENC    = (ushort*)alloc((size_t)B_*S_*H2_*2);
  ushort* ENCT   = (ushort*)alloc((size_t)B_*S_*H2_*2);
  ushort* WaH    = (ushort*)alloc((size_t)H2_*H2_*2);
  ushort* WaE    = (ushort*)alloc((size_t)H2_*H2_*2);
  ushort* Wd     = (ushort*)alloc((size_t)D4_*KXI_*2);
  float*  bsd    = (float*)alloc(D4_*4);
  ushort* WoB    = (ushort*)alloc((size_t)V_*H2_*2);
  float*  cbuf0  = (float*)alloc(B_*H2_*4);
  uint*   hU     = (uint*)alloc((size_t)2*B_*H2_*4);   // tagged h, 2 slots
  uint*   ctxU   = (uint*)alloc((size_t)2*B_*H2_*4);   // tagged ctx, 2 slots
  float*  qbuf   = (float*)alloc((size_t)2*B_*H2_*4);  // q double-buffered
  float*  scores = (float*)alloc(B_*S_*4);
  ushort* hsd    = (ushort*)alloc((size_t)MD*H2_*2);
  uint*   hgf    = (uint*)alloc((size_t)2*B_*H_*4);    // tagged encoder h (fwd)
  uint*   hgb    = (uint*)alloc((size_t)2*B_*H_*4);    // tagged encoder h (bwd)
  uint*   flags  = (uint*)alloc(4096);
  char*   big    = alloc((size_t)2*S_*B_*G4_*2);   // Xgf+Xgb; later aliased by P (f32)
  ushort* Xgf = (ushort*)big;
  ushort* Xgb = (ushort*)(big + (size_t)S_*B_*G4_*2);
  float*  P   = (float*)big;

  // ---- setup ----
  k_init<<<dim3(128), dim3(256), 0, stream>>>(flags, hgf, hgb, hU, ctxU);
  k_embed<<<dim3(S_*B_ + DSTEPS*B_), dim3(E_), 0, stream>>>(src, tgt, emb, Xb, DXb);
  k_cvt_encw<<<dim3(G4_), dim3(256), 0, stream>>>(Wih_f, Wihf_p);
  k_cvt_encw<<<dim3(G4_), dim3(256), 0, stream>>>(Wih_b, Wihb_p);
  k_bias_encp<<<dim3(8), dim3(256), 0, stream>>>(bih_f, bhh_f, bsf);
  k_bias_encp<<<dim3(8), dim3(256), 0, stream>>>(bih_b, bhh_b, bsb);
  k_cvt_strided<<<dim3(H2_), dim3(256), 0, stream>>>(Wa, WaH, H2_, 2*H2_, 0,   H2_, 0);
  k_cvt_strided<<<dim3(H2_), dim3(256), 0, stream>>>(Wa, WaE, H2_, 2*H2_, H2_, H2_, 0);
  k_cvt_decw<<<dim3(D4_), dim3(256), 0, stream>>>(Wih_d, Whh_d, Wd);
  k_bias_decp<<<dim3(16), dim3(256), 0, stream>>>(bih_d, bhh_d, bsd);
  k_cvt_strided<<<dim3(V_),  dim3(256), 0, stream>>>(Wo, WoB, H2_, H2_, 0, H2_, 0);

  // ---- encoder input-gate pre-GEMMs -> [s][col][b] layout (MODE 3) ----
  gemm128<3><<<dim3(G4_/128, (S_*B_)/128), dim3(256), 0, stream>>>(Xb, Wihf_p, bsf, Xgf, S_*B_, G4_, E_, 0);
  gemm128<3><<<dim3(G4_/128, (S_*B_)/128), dim3(256), 0, stream>>>(Xb, Wihb_p, bsb, Xgb, S_*B_, G4_, E_, 0);

  // ---- persistent bidirectional encoder (32 WGs: 16/dir), tag-synced ----
  k_enc_persist<<<dim3(32), dim3(512), 0, stream>>>(Xgf, Xgb, Whh_f, Whh_b, ENC, ENCT,
                                                    hU + B_*H2_, cbuf0, hgf, hgb);

  // ---- enc_proj = enc_out @ Wa_e^T + ba ----
  gemm128<0><<<dim3(H2_/128, (B_*S_)/128), dim3(256), 0, stream>>>(ENC, WaE, ba, P, B_*S_, H2_, H2_, 0);
  k_zero_t0<<<dim3((B_*V_+255)/256), dim3(256), 0, stream>>>(out);

  // ---- persistent decoder (256 WGs x 512 threads), tag-synced ----
  k_dec<<<dim3(NWG_DEC), dim3(512), 0, stream>>>(P, WaH, Wd, bsd, ENCT, DXb, cbuf0, hU,
                                                 ctxU, qbuf, scores, hsd, flags);

  // ---- final projection ----
  gemm128<2><<<dim3(V_/128, MD/128), dim3(256), 0, stream>>>(hsd, WoB, bo, out, MD, V_, H2_, DSTEPS*B_);
}

// Round 17
// 5574.305 us; speedup vs baseline: 1.0506x; 1.0506x over previous
//
#include <hip/hip_runtime.h>

typedef unsigned int uint;
typedef unsigned short ushort;
typedef unsigned long long ull;
typedef __attribute__((ext_vector_type(8))) short bf16x8;
typedef __attribute__((ext_vector_type(4))) float f32x4;

static constexpr int V_ = 32000, E_ = 256, H_ = 512, B_ = 16, S_ = 512, T_ = 128;
static constexpr int H2_ = 1024, G4_ = 2048, D4_ = 4096, KXI_ = 2304; // 256+1024+1024
static constexpr int DSTEPS = T_ - 1;  // 127
static constexpr int MD = 2048;        // padded rows for preds GEMM (2032 valid)
static constexpr int NWG_DEC = 256;
static constexpr float LOG2E = 1.4426950408889634f;
static constexpr int ASTR = 2312;      // AB padded row stride (ushorts)

#define DEVFN __device__ __forceinline__

DEVFN ushort f2bf(float f){ uint u = __builtin_bit_cast(uint, f); u += 0x7fffu + ((u>>16)&1u); return (ushort)(u>>16); }
DEVFN float bf2f(ushort h){ uint u = ((uint)h)<<16; return __builtin_bit_cast(float, u); }
DEVFN float fsig(float x){ float e = __builtin_amdgcn_exp2f(-LOG2E*x); return __builtin_amdgcn_rcpf(1.f+e); }
DEVFN float ftanh(float x){ x = fminf(15.f,fmaxf(-15.f,x)); float e = __builtin_amdgcn_exp2f(2.f*LOG2E*x); return (e-1.f)*__builtin_amdgcn_rcpf(e+1.f); }
DEVFN f32x4 mfma16(bf16x8 a, bf16x8 b, f32x4 c){ return __builtin_amdgcn_mfma_f32_16x16x32_bf16(a,b,c,0,0,0); }

// ---- coherent helpers: agent-scope relaxed atomics (sc1-only -> L3-served).
// NOT "sc0 sc1" system scope (HBM every access — the r5-7 regression).
struct ull2v{ ull x, y; };
DEVFN ull ald64(const void* p){ return __hip_atomic_load((const ull*)p, __ATOMIC_RELAXED, __HIP_MEMORY_SCOPE_AGENT); }
DEVFN uint ald32u(const uint* p){ return __hip_atomic_load(p, __ATOMIC_RELAXED, __HIP_MEMORY_SCOPE_AGENT); }
DEVFN float ald_f32(const float* p){ uint v = __hip_atomic_load((const uint*)p, __ATOMIC_RELAXED, __HIP_MEMORY_SCOPE_AGENT); return __builtin_bit_cast(float, v); }
DEVFN void ast32(float* p, float v){ __hip_atomic_store(p, v, __ATOMIC_RELAXED, __HIP_MEMORY_SCOPE_AGENT); }
DEVFN void ast16(ushort* p, ushort v){ __hip_atomic_store(p, v, __ATOMIC_RELAXED, __HIP_MEMORY_SCOPE_AGENT); }
DEVFN void astu(uint* p, uint v){ __hip_atomic_store(p, v, __ATOMIC_RELAXED, __HIP_MEMORY_SCOPE_AGENT); }
DEVFN void ast64(ull* p, ull v){ __hip_atomic_store(p, v, __ATOMIC_RELAXED, __HIP_MEMORY_SCOPE_AGENT); }

// f32 carried as hi/lo bf16 pair, both halves tagged: one 64-bit store moves
// data+tag atomically (no flag, no ordering concern). Reconstruction error
// ~2^-17 relative (exact split: s = bf2f(hi) + residual, residual re-rounded).
DEVFN float unpack2f(ull v){ return bf2f((ushort)v) + bf2f((ushort)(v>>32)); }
DEVFN ull pack2f(float s, uint tag){
  ushort hi = f2bf(s);
  float r = s - bf2f(hi);
  ushort lo = f2bf(r);
  return ((ull)((tag<<16)|(uint)lo)<<32) | (ull)((tag<<16)|(uint)hi);
}
DEVFN bool tagok2(ull v, uint tag){ return ((((uint)v)>>16)==tag) && ((((uint)(v>>32))>>16)==tag); }

// zero flags + tagged buffers. Exact-match tags require zero init on EVERY call
// (graph replays) so stale tags never satisfy a poll early.
__global__ void k_init(uint* __restrict__ flags, uint* __restrict__ hgf, uint* __restrict__ hgb,
                       uint* __restrict__ hU, uint* __restrict__ ctxU,
                       uint* __restrict__ qUu, uint* __restrict__ sUu){
  int i = blockIdx.x*256 + threadIdx.x;   // 32768 threads
  if (i < 1024) flags[i] = 0;
  if (i < 2*B_*H_){ hgf[i]=0u; hgb[i]=0u; }
  if (i < B_*H2_) hU[i] = 0u;
  if (i < 2*B_*H2_) ctxU[i] = 0u;
  if (i < 2*B_*H2_) qUu[i] = 0u;
  if (i < B_*S_)  { sUu[i*2] = 0u; sUu[i*2+1] = 0u; }
}

// ---------------- embedding gather ----------------
__global__ void k_embed(const int* __restrict__ src, const int* __restrict__ tgt,
                        const float* __restrict__ emb, ushort* __restrict__ Xb, ushort* __restrict__ DXb){
  int r = blockIdx.x, tid = threadIdx.x;
  if (r < S_*B_){
    int s = r>>4, b = r&15;
    int id = src[b*S_+s];
    Xb[(size_t)r*E_+tid] = f2bf(emb[(size_t)id*E_+tid]);
  } else {
    int r2 = r - S_*B_;
    int t = r2>>4, b = r2&15;
    int id = tgt[b*T_+t];
    DXb[(size_t)r2*E_+tid] = f2bf(emb[(size_t)id*E_+tid]);
  }
}

// encoder Wih convert: d: wg=d>>7, r=d&127, w=r>>4, jj=(r>>2)&3, g=r&3
// -> src row g*512 + wg*32 + w*4 + jj
__global__ void k_cvt_encw(const float* __restrict__ src, ushort* __restrict__ dst){
  int d = blockIdx.x;
  int wg = d>>7, r = d&127;
  int w = r>>4, jj=(r>>2)&3, g=r&3;
  int srow = g*H_ + wg*32 + w*4 + jj;
  for (int c = threadIdx.x; c < E_; c += 256)
    dst[(size_t)d*E_ + c] = f2bf(src[(size_t)srow*E_ + c]);
}

__global__ void k_bias_encp(const float* __restrict__ bih, const float* __restrict__ bhh, float* __restrict__ dst){
  int d = blockIdx.x*256 + threadIdx.x;
  int wg = d>>7, r = d&127;
  int w = r>>4, jj=(r>>2)&3, g=r&3;
  int srow = g*H_ + wg*32 + w*4 + jj;
  dst[d] = bih[srow]+bhh[srow];
}

// decoder Wd convert (256 WGs x 16 rows): dst row d: wg=d>>4, r=d&15,
// jj=r>>2, g=r&3 -> src row g*1024 + wg*4 + jj
__global__ void k_cvt_decw(const float* __restrict__ Wih_d, const float* __restrict__ Whh_d,
                           ushort* __restrict__ dst){
  int d = blockIdx.x;
  int wg = d>>4, r = d&15, jj = r>>2, g = r&3;
  int srow = g*H2_ + wg*4 + jj;
  for (int c = threadIdx.x; c < KXI_; c += 256){
    float v = (c < E_+H2_) ? Wih_d[(size_t)srow*(E_+H2_) + c] : Whh_d[(size_t)srow*H2_ + (c - (E_+H2_))];
    dst[(size_t)d*KXI_ + c] = f2bf(v);
  }
}

__global__ void k_bias_decp(const float* __restrict__ bih, const float* __restrict__ bhh, float* __restrict__ dst){
  int d = blockIdx.x*256 + threadIdx.x;
  int wg = d>>4, r = d&15, jj = r>>2, g = r&3;
  int srow = g*H2_ + wg*4 + jj;
  dst[d] = bih[srow]+bhh[srow];
}

__global__ void k_cvt_strided(const float* __restrict__ src, ushort* __restrict__ dst,
                              int cols, int sld, int soff, int dld, int doff){
  int r = blockIdx.x;
  for (int c = threadIdx.x; c < cols; c += 256)
    dst[(size_t)r*dld + doff + c] = f2bf(src[(size_t)r*sld + soff + c]);
}

__global__ void k_zero_t0(float* __restrict__ out){
  int i = blockIdx.x*256 + threadIdx.x;
  if (i < B_*V_){ int b = i / V_, v = i - b*V_; out[(size_t)b*T_*V_ + v] = 0.f; }
}

// ---------------- 128x128-tile bf16 MFMA GEMM ----------------
template<int MODE>
__global__ __launch_bounds__(256) void gemm128(const ushort* __restrict__ A, const ushort* __restrict__ Bm,
    const float* __restrict__ bias, void* __restrict__ outp, int M, int N, int K, int Mvalid){
  __shared__ __align__(16) ushort As[128*32];
  __shared__ __align__(16) ushort Bs[128*32];
  int tid = threadIdx.x;
  int wave = tid>>6, lane = tid&63;
  int m0 = blockIdx.y*128, n0 = blockIdx.x*128;
  int wm = wave>>1, wn = wave&1;
  int col = lane&15, rg = lane>>4;
  f32x4 acc[4][4];
  #pragma unroll
  for (int i=0;i<4;i++)
    #pragma unroll
    for (int j=0;j<4;j++) acc[i][j] = {0.f,0.f,0.f,0.f};
  for (int k0=0;k0<K;k0+=32){
    __syncthreads();
    #pragma unroll
    for (int j=0;j<2;j++){
      int li = j*256+tid;
      int row = li>>2, ko = (li&3)*8;
      *(bf16x8*)(As + li*8) = *(const bf16x8*)(A + (size_t)(m0+row)*K + k0 + ko);
      *(bf16x8*)(Bs + li*8) = *(const bf16x8*)(Bm + (size_t)(n0+row)*K + k0 + ko);
    }
    __syncthreads();
    bf16x8 af[4], bfr[4];
    #pragma unroll
    for (int f=0;f<4;f++){
      af[f]  = *(const bf16x8*)(As + (wm*64+f*16+col)*32 + rg*8);
      bfr[f] = *(const bf16x8*)(Bs + (wn*64+f*16+col)*32 + rg*8);
    }
    #pragma unroll
    for (int fm=0;fm<4;fm++)
      #pragma unroll
      for (int fn=0;fn<4;fn++)
        acc[fm][fn] = mfma16(af[fm], bfr[fn], acc[fm][fn]);
  }
  #pragma unroll
  for (int fm=0;fm<4;fm++){
    int mrow = m0 + wm*64 + fm*16 + rg*4;
    #pragma unroll
    for (int fn=0;fn<4;fn++){
      int gcol = n0 + wn*64 + fn*16 + col;
      float bv = bias ? bias[gcol] : 0.f;
      #pragma unroll
      for (int i=0;i<4;i++){
        float v = acc[fm][fn][i] + bv;
        int grow = mrow + i;
        if (MODE==0) ((float*)outp)[(size_t)grow*N + gcol] = v;
        else if (MODE==1) ((ushort*)outp)[(size_t)grow*N + gcol] = f2bf(v);
        else if (MODE==3) ((ushort*)outp)[(size_t)(grow>>4)*(16*2048) + gcol*16 + (grow&15)] = f2bf(v);
        else { if (grow < Mvalid){ int b = grow&15, t = grow>>4;
               ((float*)outp)[(size_t)b*T_*V_ + (size_t)(t+1)*V_ + gcol] = v; } }
      }
    }
  }
}

// ---------------- persistent bidirectional encoder: 16 WGs/dir x 512 thr (r14) ----------------
__global__ __launch_bounds__(512) void k_enc_persist(
    const ushort* __restrict__ Xgf, const ushort* __restrict__ Xgb,
    const float* __restrict__ Whhf, const float* __restrict__ Whhb,
    ushort* __restrict__ enc, ushort* __restrict__ enct,
    uint* __restrict__ hbuf1, float* __restrict__ cbuf0,
    uint* __restrict__ hgf, uint* __restrict__ hgb){
  const int dir = blockIdx.x >> 4;
  const int wg  = blockIdx.x & 15;
  const ushort* Xg = dir ? Xgb : Xgf;
  const float* Whh = dir ? Whhb : Whhf;
  uint* hg = dir ? hgb : hgf;
  __shared__ __align__(16) ushort Wlds[128*512];   // 128 KiB, XOR-swizzled
  __shared__ __align__(16) ushort hls[16*512];     // 16 KiB staged h, XOR-swizzled
  int tid = threadIdx.x;
  for (int it=0; it<32; ++it){
    int r = it*4 + (tid>>7), ct = tid&127;
    int w_ = r>>4, jj=(r>>2)&3, g=r&3;
    int srow = g*H_ + wg*32 + w_*4 + jj;
    float4 v = *(const float4*)(Whh + (size_t)srow*H_ + ct*4);
    ushort4 o; o.x=f2bf(v.x); o.y=f2bf(v.y); o.z=f2bf(v.z); o.w=f2bf(v.w);
    int byte = (r*1024 + ct*8) ^ ((r&7)<<4);
    *(ushort4*)((char*)Wlds + byte) = o;
  }
  int w = tid>>6, lane = tid&63, colL = lane&15, rg = lane>>4;
  int gg = colL&3;
  float cst[4];
  #pragma unroll
  for (int i=0;i<4;i++) cst[i]=0.f;
  __syncthreads();
  for (int t=0;t<S_;++t){
    int pos = dir ? (S_-1-t) : t;
    const uint* hsrcU = hg + (t&1)*B_*H_;
    // tag-poll h_t: want tag == t (t=0: zeros, tag 0)
    uint uu[16];
    for(;;){
      #pragma unroll
      for (int k2=0;k2<2;k2++){
        int idx = tid + k2*512;
        const uint* p = hsrcU + (idx>>6)*H_ + (idx&63)*8;
        #pragma unroll
        for (int j=0;j<4;j++){
          ull v = ald64(p + j*2);
          uu[k2*8+j*2] = (uint)v; uu[k2*8+j*2+1] = (uint)(v>>32);
        }
      }
      bool ok = true;
      #pragma unroll
      for (int i2=0;i2<16;i2++) ok &= ((uu[i2]>>16) == (uint)t);
      if (ok) break;
      __builtin_amdgcn_s_sleep(1);
    }
    int colg = wg*128 + w*16 + colL;
    ushort4 xv = *(const ushort4*)(Xg + ((size_t)pos*2048 + colg)*16 + rg*4);
    f32x4 acc;
    acc[0]=bf2f(xv.x); acc[1]=bf2f(xv.y); acc[2]=bf2f(xv.z); acc[3]=bf2f(xv.w);
    #pragma unroll
    for (int k2=0;k2<2;k2++){
      int idx = tid + k2*512;
      int byte = ((idx>>6)*1024 + (idx&63)*16) ^ (((idx>>6)&7)<<4);
      ushort tmp[8];
      #pragma unroll
      for (int j=0;j<8;j++) tmp[j] = (ushort)uu[k2*8+j];
      *(bf16x8*)((char*)hls + byte) = *(bf16x8*)tmp;
    }
    __syncthreads();
    int rowb = w*16 + colL;
    int base = rowb*1024 + rg*16, xm = (rowb&7)<<4;
    int hbase = colL*1024 + rg*16, hxm = (colL&7)<<4;
    #pragma unroll
    for (int kt=0;kt<16;kt++){
      bf16x8 afv = *(const bf16x8*)((const char*)hls + ((hbase + kt*64) ^ hxm));
      bf16x8 bfv = *(const bf16x8*)((const char*)Wlds + ((base + kt*64) ^ xm));
      acc = mfma16(afv, bfv, acc);
    }
    uint* hdstU = hg + ((t+1)&1)*B_*H_;
    #pragma unroll
    for (int i=0;i<4;i++){
      float v0 = acc[i];
      float v1 = __shfl_xor(v0, 1);
      float v2 = __shfl_xor(v0, 2);
      float v3 = __shfl_xor(v1, 2);
      float zi = gg==0?v0: gg==1?v1: gg==2?v2: v3;
      float zf = (gg^1)==0?v0: (gg^1)==1?v1: (gg^1)==2?v2: v3;
      float zg = (gg^2)==0?v0: (gg^2)==1?v1: (gg^2)==2?v2: v3;
      float zo = (gg^3)==0?v0: (gg^3)==1?v1: (gg^3)==2?v2: v3;
      float cc = fsig(zf)*cst[i] + fsig(zi)*ftanh(zg);
      cst[i] = cc;
      float h = fsig(zo)*ftanh(cc);
      if (gg==0){
        int j = wg*32 + w*4 + (colL>>2);
        int b = rg*4+i;
        ushort hb = f2bf(h);
        enc[((size_t)b*S_ + pos)*H2_ + dir*H_ + j] = hb;
        enct[((size_t)b*H2_ + dir*H_ + j)*S_ + pos] = hb;
        astu(&hdstU[b*H_ + j], (uint)hb | ((uint)(t+1)<<16));
        if (t==S_-1){
          hbuf1[b*H2_ + dir*H_ + j] = (uint)hb;  // decoder h0, tag 0
          cbuf0[b*H2_ + dir*H_ + j] = cc;        // decoder c0
        }
      }
    }
    __syncthreads();   // protect hls reuse across steps
  }
}

// ---------------- persistent decoder: 256 WGs x 512 threads, all-tag sync ----------------
// Every cross-WG handoff is an in-band tagged data word: h/ctx (bf16+tag),
// q/scores (hi/lo bf16 pair, both tagged, one 64-bit store). Zero flag barriers.
// Race-safety: the dependency cycle q->scores->ctx->h->q orders every overwrite
// behind all reads of the previous value; exact-match step tags do the rest.
__global__ __launch_bounds__(512) void k_dec(
    const float* __restrict__ P, const ushort* __restrict__ WaH,
    const ushort* __restrict__ Wd, const float* __restrict__ bsd,
    const ushort* __restrict__ enct, const ushort* __restrict__ DXb,
    const float* __restrict__ cbuf0, uint* __restrict__ hU,
    uint* __restrict__ ctxU, ull* __restrict__ qU,
    ull* __restrict__ sU, ushort* __restrict__ hsd){
  __shared__ __align__(16) ushort AB[16*ASTR];   // 74KB phase-D xi stage
  __shared__ __align__(16) float pr[8*256];
  __shared__ float redz[256];
  __shared__ float qls[1024];
  __shared__ float wls[512];
  __shared__ float part[512];
  __shared__ float red[16];
  __shared__ float cst[64];
  int wgid = blockIdx.x, tid = threadIdx.x;
  int w = tid>>6, lane = tid&63, colL = lane&15, rg = lane>>4;
  int b = wgid>>4, wc = wgid&15;
  if (tid < 64){
    int jj = tid>>4, b4 = tid&15;
    cst[tid] = cbuf0[b4*H2_ + wgid*4 + jj];
  }
  for (int st=0; st<DSTEPS; ++st){
    const uint* hprevU = hU + ((st+1)&1)*B_*H2_;
    uint* cslot = ctxU + (st&1)*B_*H2_;
    const uint wantH = (uint)st;
    const uint wantT = (uint)(st+1);   // q / scores / ctx / h-out tags
    // ---- phase A: q = h_{t-1} @ WaH^T (WGs 64..127); h tag-poll, q tagged out ----
    if (wgid >= 64 && wgid < 128){
      int n0 = (wgid-64)*16;
      const uint* hp = hprevU + colL*H2_ + w*128 + rg*8;
      uint uu[32];
      for(;;){
        #pragma unroll
        for (int kt=0;kt<4;kt++)
          #pragma unroll
          for (int j=0;j<4;j++){
            ull v = ald64(hp + kt*32 + j*2);
            uu[kt*8+j*2] = (uint)v; uu[kt*8+j*2+1] = (uint)(v>>32);
          }
        bool ok = true;
        #pragma unroll
        for (int i2=0;i2<32;i2++) ok &= ((uu[i2]>>16) == wantH);
        if (ok) break;
        __builtin_amdgcn_s_sleep(1);
      }
      f32x4 acc = {0.f,0.f,0.f,0.f};
      const ushort* Bp = WaH + (size_t)(n0+colL)*H2_ + w*128 + rg*8;
      #pragma unroll
      for (int kt=0;kt<4;kt++){
        ushort tmp[8];
        #pragma unroll
        for (int j=0;j<8;j++) tmp[j] = (ushort)uu[kt*8+j];
        acc = mfma16(*(bf16x8*)tmp, *(const bf16x8*)(Bp + kt*32), acc);
      }
      *(f32x4*)&pr[w*256 + lane*4] = acc;
      __syncthreads();
      if (tid < 256){
        float s = pr[tid];
        #pragma unroll
        for (int w8=1;w8<8;w8++) s += pr[w8*256 + tid];
        int l = tid>>2, i = tid&3;
        ast64(&qU[(size_t)((l>>4)*4 + i)*H2_ + n0 + (l&15)], pack2f(s, wantT));
      }
    }
    // ---- phase B: poll q data (in-band), scores = sum_k tanh(P + q) ----
    {
      const ull* qp = qU + (size_t)b*H2_;
      ull v0, v1;
      for(;;){
        v0 = ald64(qp + tid*2);
        v1 = ald64(qp + tid*2 + 1);
        if (tagok2(v0, wantT) && tagok2(v1, wantT)) break;
        __builtin_amdgcn_s_sleep(1);
      }
      qls[tid*2]   = unpack2f(v0);
      qls[tid*2+1] = unpack2f(v1);
      __syncthreads();
      f32x4 qv[4];
      #pragma unroll
      for (int u=0;u<4;u++) qv[u] = *(const f32x4*)&qls[lane*16 + u*4];
      int rbase = b*S_ + wc*32 + w*4;
      #pragma unroll
      for (int rr=0;rr<4;rr++){
        int r = rbase + rr;
        const float4* Pr = (const float4*)(P + (size_t)r*H2_) + lane*4;
        float s = 0.f;
        #pragma unroll
        for (int u=0;u<4;u++){
          float4 pv = Pr[u];
          s += ftanh(pv.x+qv[u][0])+ftanh(pv.y+qv[u][1])+ftanh(pv.z+qv[u][2])+ftanh(pv.w+qv[u][3]);
        }
        #pragma unroll
        for (int o=32;o;o>>=1) s += __shfl_xor(s,o);
        if (lane==0) ast64(&sU[r], pack2f(s, wantT));
      }
    }
    __syncthreads();
    // ---- phase C: poll scores data (in-band), softmax + ctx; ctx TAGGED ----
    {
      ull sv;
      const ull* sp = sU + (size_t)b*S_ + tid;
      for(;;){
        sv = ald64(sp);
        if (tagok2(sv, wantT)) break;
        __builtin_amdgcn_s_sleep(1);
      }
      float sc = unpack2f(sv);
      float m = sc;
      #pragma unroll
      for (int o=32;o;o>>=1) m = fmaxf(m, __shfl_xor(m,o));
      if (lane==0) red[w] = m;
      __syncthreads();
      m = red[0];
      #pragma unroll
      for (int k2=1;k2<8;k2++) m = fmaxf(m, red[k2]);
      float e = __builtin_amdgcn_exp2f((sc - m)*LOG2E);
      float ss = e;
      #pragma unroll
      for (int o=32;o;o>>=1) ss += __shfl_xor(ss,o);
      if (lane==0) red[8+w] = ss;
      __syncthreads();
      float tot = red[8];
      #pragma unroll
      for (int k2=9;k2<16;k2++) tot += red[k2];
      wls[tid] = e * __builtin_amdgcn_rcpf(tot);
      __syncthreads();
      int c = wc*64 + (tid&63), sseg = tid>>6;
      const ushort* ep = enct + ((size_t)b*H2_ + c)*S_ + sseg*64;
      float a = 0.f;
      #pragma unroll
      for (int u=0;u<8;u++){
        bf16x8 ev = *(const bf16x8*)(ep + u*8);
        #pragma unroll
        for (int j=0;j<8;j++) a += wls[sseg*64 + u*8 + j] * bf2f((ushort)ev[j]);
      }
      part[tid] = a;
      __syncthreads();
      if (tid < 64){
        float s = part[tid];
        #pragma unroll
        for (int g2=1;g2<8;g2++) s += part[g2*64 + tid];
        astu(&cslot[b*H2_ + wc*64 + tid], (uint)f2bf(s) | (wantT<<16));
      }
    }
    // ---- phase D: merged ctx+h tag-poll, stage, gates MFMA (k-split 8x288), cell ----
    {
      { int b3 = tid>>5, seg = tid&31;
        *(bf16x8*)&AB[b3*ASTR + seg*8] = *(const bf16x8*)(DXb + (size_t)(st*16+b3)*E_ + seg*8); }
      uint uc[32], uh[32];
      for(;;){
        #pragma unroll
        for (int k2=0;k2<4;k2++){
          int idx = tid + k2*512;
          const uint* pc = cslot  + (idx>>7)*H2_ + (idx&127)*8;
          const uint* ph = hprevU + (idx>>7)*H2_ + (idx&127)*8;
          #pragma unroll
          for (int j=0;j<4;j++){
            ull vc = ald64(pc + j*2);
            ull vh = ald64(ph + j*2);
            uc[k2*8+j*2] = (uint)vc; uc[k2*8+j*2+1] = (uint)(vc>>32);
            uh[k2*8+j*2] = (uint)vh; uh[k2*8+j*2+1] = (uint)(vh>>32);
          }
        }
        bool ok = true;
        #pragma unroll
        for (int i2=0;i2<32;i2++) ok &= ((uc[i2]>>16) == wantT) && ((uh[i2]>>16) == wantH);
        if (ok) break;
        __builtin_amdgcn_s_sleep(1);
      }
      #pragma unroll
      for (int k2=0;k2<4;k2++){
        int idx = tid + k2*512;
        ushort tc[8], th[8];
        #pragma unroll
        for (int j=0;j<8;j++){ tc[j] = (ushort)uc[k2*8+j]; th[j] = (ushort)uh[k2*8+j]; }
        *(bf16x8*)&AB[(idx>>7)*ASTR + 256  + (idx&127)*8] = *(bf16x8*)tc;
        *(bf16x8*)&AB[(idx>>7)*ASTR + 1280 + (idx&127)*8] = *(bf16x8*)th;
      }
      __syncthreads();
      int row0 = wgid*16;
      f32x4 acc = {0.f,0.f,0.f,0.f};
      const ushort* Bp = Wd + (size_t)(row0+colL)*KXI_ + w*288 + rg*8;
      const ushort* Apb = &AB[colL*ASTR + w*288 + rg*8];
      #pragma unroll
      for (int kt=0;kt<9;kt++)
        acc = mfma16(*(const bf16x8*)(Apb + kt*32), *(const bf16x8*)(Bp + kt*32), acc);
      *(f32x4*)&pr[w*256 + lane*4] = acc;
      __syncthreads();
      if (tid < 256){
        float s = bsd[row0 + ((tid>>2)&15)];
        #pragma unroll
        for (int w8=0;w8<8;w8++) s += pr[w8*256 + tid];
        redz[tid] = s;
      }
      __syncthreads();
      if (tid < 64){
        int jj = tid>>4, b4 = tid&15, rgc = b4>>2, ic = b4&3;
        float zi = redz[((jj*4+0) + 16*rgc)*4 + ic];
        float zf = redz[((jj*4+1) + 16*rgc)*4 + ic];
        float zg = redz[((jj*4+2) + 16*rgc)*4 + ic];
        float zo = redz[((jj*4+3) + 16*rgc)*4 + ic];
        float cc2 = fsig(zf)*cst[tid] + fsig(zi)*ftanh(zg);
        cst[tid] = cc2;
        float h = fsig(zo)*ftanh(cc2);
        ushort hb = f2bf(h);
        int j = wgid*4 + jj;
        astu(&hU[(st&1)*B_*H2_ + b4*H2_ + j], (uint)hb | (wantT<<16));
        hsd[((size_t)st*B_ + b4)*H2_ + j] = hb;
      }
      __syncthreads();
    }
  }
}

extern "C" void kernel_launch(void* const* d_in, const int* in_sizes, int n_in,
                              void* d_out, int out_size, void* d_ws, size_t ws_size,
                              hipStream_t stream) {
  const int* src   = (const int*)d_in[0];
  const int* tgt   = (const int*)d_in[1];
  const float* emb   = (const float*)d_in[2];
  const float* Wih_f = (const float*)d_in[3];
  const float* Whh_f = (const float*)d_in[4];
  const float* bih_f = (const float*)d_in[5];
  const float* bhh_f = (const float*)d_in[6];
  const float* Wih_b = (const float*)d_in[7];
  const float* Whh_b = (const float*)d_in[8];
  const float* bih_b = (const float*)d_in[9];
  const float* bhh_b = (const float*)d_in[10];
  const float* Wih_d = (const float*)d_in[11];
  const float* Whh_d = (const float*)d_in[12];
  const float* bih_d = (const float*)d_in[13];
  const float* bhh_d = (const float*)d_in[14];
  const float* Wa    = (const float*)d_in[15];
  const float* ba    = (const float*)d_in[16];
  const float* Wo    = (const float*)d_in[17];
  const float* bo    = (const float*)d_in[18];
  float* out = (float*)d_out;
  (void)in_sizes; (void)n_in; (void)out_size; (void)ws_size;

  char* ws = (char*)d_ws;
  size_t off = 0;
  auto alloc = [&](size_t bytes)->char*{ char* p = ws + off; off += (bytes + 255) & ~(size_t)255; return p; };
  ushort* Xb     = (ushort*)alloc((size_t)S_*B_*E_*2);
  ushort* DXb    = (ushort*)alloc((size_t)DSTEPS*B_*E_*2);
  ushort* Wihf_p = (ushort*)alloc((size_t)G4_*E_*2);
  ushort* Wihb_p = (ushort*)alloc((size_t)G4_*E_*2);
  float*  bsf    = (float*)alloc(G4_*4);
  float*  bsb    = (float*)alloc(G4_*4);
  ushort* ENC    = (ushort*)alloc((size_t)B_*S_*H2_*2);
  ushort* ENCT   = (ushort*)alloc((size_t)B_*S_*H2_*2);
  ushort* WaH    = (ushort*)alloc((size_t)H2_*H2_*2);
  ushort* WaE    = (ushort*)alloc((size_t)H2_*H2_*2);
  ushort* Wd     = (ushort*)alloc((size_t)D4_*KXI_*2);
  float*  bsd    = (float*)alloc(D4_*4);
  ushort* WoB    = (ushort*)alloc((size_t)V_*H2_*2);
  float*  cbuf0  = (float*)alloc(B_*H2_*4);
  uint*   hU     = (uint*)alloc((size_t)2*B_*H2_*4);   // tagged h, 2 slots
  uint*   ctxU   = (uint*)alloc((size_t)2*B_*H2_*4);   // tagged ctx, 2 slots
  ull*    qU     = (ull*)alloc((size_t)B_*H2_*8);      // tagged hi/lo q
  ull*    sU     = (ull*)alloc((size_t)B_*S_*8);       // tagged hi/lo scores
  ushort* hsd    = (ushort*)alloc((size_t)MD*H2_*2);
  uint*   hgf    = (uint*)alloc((size_t)2*B_*H_*4);    // tagged encoder h (fwd)
  uint*   hgb    = (uint*)alloc((size_t)2*B_*H_*4);    // tagged encoder h (bwd)
  uint*   flags  = (uint*)alloc(4096);
  char*   big    = alloc((size_t)2*S_*B_*G4_*2);   // Xgf+Xgb; later aliased by P (f32)
  ushort* Xgf = (ushort*)big;
  ushort* Xgb = (ushort*)(big + (size_t)S_*B_*G4_*2);
  float*  P   = (float*)big;

  // ---- setup ----
  k_init<<<dim3(128), dim3(256), 0, stream>>>(flags, hgf, hgb, hU, ctxU, (uint*)qU, (uint*)sU);
  k_embed<<<dim3(S_*B_ + DSTEPS*B_), dim3(E_), 0, stream>>>(src, tgt, emb, Xb, DXb);
  k_cvt_encw<<<dim3(G4_), dim3(256), 0, stream>>>(Wih_f, Wihf_p);
  k_cvt_encw<<<dim3(G4_), dim3(256), 0, stream>>>(Wih_b, Wihb_p);
  k_bias_encp<<<dim3(8), dim3(256), 0, stream>>>(bih_f, bhh_f, bsf);
  k_bias_encp<<<dim3(8), dim3(256), 0, stream>>>(bih_b, bhh_b, bsb);
  k_cvt_strided<<<dim3(H2_), dim3(256), 0, stream>>>(Wa, WaH, H2_, 2*H2_, 0,   H2_, 0);
  k_cvt_strided<<<dim3(H2_), dim3(256), 0, stream>>>(Wa, WaE, H2_, 2*H2_, H2_, H2_, 0);
  k_cvt_decw<<<dim3(D4_), dim3(256), 0, stream>>>(Wih_d, Whh_d, Wd);
  k_bias_decp<<<dim3(16), dim3(256), 0, stream>>>(bih_d, bhh_d, bsd);
  k_cvt_strided<<<dim3(V_),  dim3(256), 0, stream>>>(Wo, WoB, H2_, H2_, 0, H2_, 0);

  // ---- encoder input-gate pre-GEMMs -> [s][col][b] layout (MODE 3) ----
  gemm128<3><<<dim3(G4_/128, (S_*B_)/128), dim3(256), 0, stream>>>(Xb, Wihf_p, bsf, Xgf, S_*B_, G4_, E_, 0);
  gemm128<3><<<dim3(G4_/128, (S_*B_)/128), dim3(256), 0, stream>>>(Xb, Wihb_p, bsb, Xgb, S_*B_, G4_, E_, 0);

  // ---- persistent bidirectional encoder (32 WGs: 16/dir), tag-synced ----
  k_enc_persist<<<dim3(32), dim3(512), 0, stream>>>(Xgf, Xgb, Whh_f, Whh_b, ENC, ENCT,
                                                    hU + B_*H2_, cbuf0, hgf, hgb);

  // ---- enc_proj = enc_out @ Wa_e^T + ba ----
  gemm128<0><<<dim3(H2_/128, (B_*S_)/128), dim3(256), 0, stream>>>(ENC, WaE, ba, P, B_*S_, H2_, H2_, 0);
  k_zero_t0<<<dim3((B_*V_+255)/256), dim3(256), 0, stream>>>(out);

  // ---- persistent decoder (256 WGs x 512 threads), all-tag sync ----
  k_dec<<<dim3(NWG_DEC), dim3(512), 0, stream>>>(P, WaH, Wd, bsd, ENCT, DXb, cbuf0, hU,
                                                 ctxU, qU, sU, hsd);

  // ---- final projection ----
  gemm128<2><<<dim3(V_/128, MD/128), dim3(256), 0, stream>>>(hsd, WoB, bo, out, MD, V_, H2_, DSTEPS*B_);
}

// Round 18
// 5532.253 us; speedup vs baseline: 1.0586x; 1.0076x over previous
//
#include <hip/hip_runtime.h>

typedef unsigned int uint;
typedef unsigned short ushort;
typedef unsigned long long ull;
typedef __attribute__((ext_vector_type(8))) short bf16x8;
typedef __attribute__((ext_vector_type(4))) float f32x4;

static constexpr int V_ = 32000, E_ = 256, H_ = 512, B_ = 16, S_ = 512, T_ = 128;
static constexpr int H2_ = 1024, G4_ = 2048, D4_ = 4096, KXI_ = 2304; // 256+1024+1024
static constexpr int DSTEPS = T_ - 1;  // 127
static constexpr int MD = 2048;        // padded rows for preds GEMM (2032 valid)
static constexpr int NWG_DEC = 256;
static constexpr float LOG2E = 1.4426950408889634f;
static constexpr int ASTR = 2312;      // AB padded row stride (ushorts)

#define DEVFN __device__ __forceinline__

DEVFN ushort f2bf(float f){ uint u = __builtin_bit_cast(uint, f); u += 0x7fffu + ((u>>16)&1u); return (ushort)(u>>16); }
DEVFN float bf2f(ushort h){ uint u = ((uint)h)<<16; return __builtin_bit_cast(float, u); }
DEVFN float fsig(float x){ float e = __builtin_amdgcn_exp2f(-LOG2E*x); return __builtin_amdgcn_rcpf(1.f+e); }
DEVFN float ftanh(float x){ x = fminf(15.f,fmaxf(-15.f,x)); float e = __builtin_amdgcn_exp2f(2.f*LOG2E*x); return (e-1.f)*__builtin_amdgcn_rcpf(e+1.f); }
DEVFN f32x4 mfma16(bf16x8 a, bf16x8 b, f32x4 c){ return __builtin_amdgcn_mfma_f32_16x16x32_bf16(a,b,c,0,0,0); }

// async global->LDS, 16B/lane (guide m97: +67% GEMM vs VGPR round-trip).
// LDS dest must be wave-uniform base; HW adds lane*16.
#define GLD_LDS16(g, l) __builtin_amdgcn_global_load_lds( \
    (const __attribute__((address_space(1))) void*)(g), \
    (__attribute__((address_space(3))) void*)(l), 16, 0, 0)

// ---- coherent helpers: agent-scope relaxed atomics (sc1-only -> L3-served).
// NOT "sc0 sc1" system scope (HBM every access — the r5-7 regression).
struct ull2v{ ull x, y; };
DEVFN ull ald64(const void* p){ return __hip_atomic_load((const ull*)p, __ATOMIC_RELAXED, __HIP_MEMORY_SCOPE_AGENT); }
DEVFN uint ald32u(const uint* p){ return __hip_atomic_load(p, __ATOMIC_RELAXED, __HIP_MEMORY_SCOPE_AGENT); }
DEVFN float ald_f32(const float* p){ uint v = __hip_atomic_load((const uint*)p, __ATOMIC_RELAXED, __HIP_MEMORY_SCOPE_AGENT); return __builtin_bit_cast(float, v); }
DEVFN void ast32(float* p, float v){ __hip_atomic_store(p, v, __ATOMIC_RELAXED, __HIP_MEMORY_SCOPE_AGENT); }
DEVFN void ast16(ushort* p, ushort v){ __hip_atomic_store(p, v, __ATOMIC_RELAXED, __HIP_MEMORY_SCOPE_AGENT); }
DEVFN void astu(uint* p, uint v){ __hip_atomic_store(p, v, __ATOMIC_RELAXED, __HIP_MEMORY_SCOPE_AGENT); }
DEVFN void ast64(ull* p, ull v){ __hip_atomic_store(p, v, __ATOMIC_RELAXED, __HIP_MEMORY_SCOPE_AGENT); }

// f32 carried as hi/lo bf16 pair, both halves tagged: one 64-bit store moves
// data+tag atomically. Reconstruction error ~2^-17 relative.
DEVFN float unpack2f(ull v){ return bf2f((ushort)v) + bf2f((ushort)(v>>32)); }
DEVFN ull pack2f(float s, uint tag){
  ushort hi = f2bf(s);
  float r = s - bf2f(hi);
  ushort lo = f2bf(r);
  return ((ull)((tag<<16)|(uint)lo)<<32) | (ull)((tag<<16)|(uint)hi);
}
DEVFN bool tagok2(ull v, uint tag){ return ((((uint)v)>>16)==tag) && ((((uint)(v>>32))>>16)==tag); }

// zero flags + tagged buffers on EVERY call (graph replays): stale tags must
// never satisfy a poll early.
__global__ void k_init(uint* __restrict__ flags, uint* __restrict__ hgf, uint* __restrict__ hgb,
                       uint* __restrict__ hU, uint* __restrict__ ctxU,
                       uint* __restrict__ qUu, uint* __restrict__ sUu){
  int i = blockIdx.x*256 + threadIdx.x;   // 32768 threads
  if (i < 1024) flags[i] = 0;
  if (i < 2*B_*H_){ hgf[i]=0u; hgb[i]=0u; }
  if (i < B_*H2_) hU[i] = 0u;
  if (i < 2*B_*H2_) ctxU[i] = 0u;
  if (i < 2*B_*H2_) qUu[i] = 0u;
  if (i < B_*S_)  { sUu[i*2] = 0u; sUu[i*2+1] = 0u; }
}

// ---------------- embedding gather ----------------
__global__ void k_embed(const int* __restrict__ src, const int* __restrict__ tgt,
                        const float* __restrict__ emb, ushort* __restrict__ Xb, ushort* __restrict__ DXb){
  int r = blockIdx.x, tid = threadIdx.x;
  if (r < S_*B_){
    int s = r>>4, b = r&15;
    int id = src[b*S_+s];
    Xb[(size_t)r*E_+tid] = f2bf(emb[(size_t)id*E_+tid]);
  } else {
    int r2 = r - S_*B_;
    int t = r2>>4, b = r2&15;
    int id = tgt[b*T_+t];
    DXb[(size_t)r2*E_+tid] = f2bf(emb[(size_t)id*E_+tid]);
  }
}

// encoder Wih convert: d: wg=d>>7, r=d&127, w=r>>4, jj=(r>>2)&3, g=r&3
// -> src row g*512 + wg*32 + w*4 + jj
__global__ void k_cvt_encw(const float* __restrict__ src, ushort* __restrict__ dst){
  int d = blockIdx.x;
  int wg = d>>7, r = d&127;
  int w = r>>4, jj=(r>>2)&3, g=r&3;
  int srow = g*H_ + wg*32 + w*4 + jj;
  for (int c = threadIdx.x; c < E_; c += 256)
    dst[(size_t)d*E_ + c] = f2bf(src[(size_t)srow*E_ + c]);
}

__global__ void k_bias_encp(const float* __restrict__ bih, const float* __restrict__ bhh, float* __restrict__ dst){
  int d = blockIdx.x*256 + threadIdx.x;
  int wg = d>>7, r = d&127;
  int w = r>>4, jj=(r>>2)&3, g=r&3;
  int srow = g*H_ + wg*32 + w*4 + jj;
  dst[d] = bih[srow]+bhh[srow];
}

// decoder Wd convert (256 WGs x 16 rows): dst row d: wg=d>>4, r=d&15,
// jj=r>>2, g=r&3 -> src row g*1024 + wg*4 + jj
__global__ void k_cvt_decw(const float* __restrict__ Wih_d, const float* __restrict__ Whh_d,
                           ushort* __restrict__ dst){
  int d = blockIdx.x;
  int wg = d>>4, r = d&15, jj = r>>2, g = r&3;
  int srow = g*H2_ + wg*4 + jj;
  for (int c = threadIdx.x; c < KXI_; c += 256){
    float v = (c < E_+H2_) ? Wih_d[(size_t)srow*(E_+H2_) + c] : Whh_d[(size_t)srow*H2_ + (c - (E_+H2_))];
    dst[(size_t)d*KXI_ + c] = f2bf(v);
  }
}

__global__ void k_bias_decp(const float* __restrict__ bih, const float* __restrict__ bhh, float* __restrict__ dst){
  int d = blockIdx.x*256 + threadIdx.x;
  int wg = d>>4, r = d&15, jj = r>>2, g = r&3;
  int srow = g*H2_ + wg*4 + jj;
  dst[d] = bih[srow]+bhh[srow];
}

__global__ void k_cvt_strided(const float* __restrict__ src, ushort* __restrict__ dst,
                              int cols, int sld, int soff, int dld, int doff){
  int r = blockIdx.x;
  for (int c = threadIdx.x; c < cols; c += 256)
    dst[(size_t)r*dld + doff + c] = f2bf(src[(size_t)r*sld + soff + c]);
}

__global__ void k_zero_t0(float* __restrict__ out){
  int i = blockIdx.x*256 + threadIdx.x;
  if (i < B_*V_){ int b = i / V_, v = i - b*V_; out[(size_t)b*T_*V_ + v] = 0.f; }
}

// ---------------- 128x128-tile bf16 MFMA GEMM (m97-style global_load_lds staging) ----------------
template<int MODE>
__global__ __launch_bounds__(256) void gemm128(const ushort* __restrict__ A, const ushort* __restrict__ Bm,
    const float* __restrict__ bias, void* __restrict__ outp, int M, int N, int K, int Mvalid){
  __shared__ __align__(16) ushort As[128*32];
  __shared__ __align__(16) ushort Bs[128*32];
  int tid = threadIdx.x;
  int wave = tid>>6, lane = tid&63;
  int m0 = blockIdx.y*128, n0 = blockIdx.x*128;
  int wm = wave>>1, wn = wave&1;
  int col = lane&15, rg = lane>>4;
  f32x4 acc[4][4];
  #pragma unroll
  for (int i=0;i<4;i++)
    #pragma unroll
    for (int j=0;j<4;j++) acc[i][j] = {0.f,0.f,0.f,0.f};
  for (int k0=0;k0<K;k0+=32){
    __syncthreads();   // previous compute done before LDS overwrite
    {
      int li0 = wave*64;            // wave-uniform chunk base
      #pragma unroll
      for (int j=0;j<2;j++){
        int lj = li0 + j*256 + lane;
        int row = lj>>2, ko = (lj&3)*8;
        GLD_LDS16(A  + (size_t)(m0+row)*K + k0 + ko, As + (size_t)(li0 + j*256)*8);
        GLD_LDS16(Bm + (size_t)(n0+row)*K + k0 + ko, Bs + (size_t)(li0 + j*256)*8);
      }
    }
    __syncthreads();   // drains vmcnt -> staged data visible
    bf16x8 af[4], bfr[4];
    #pragma unroll
    for (int f=0;f<4;f++){
      af[f]  = *(const bf16x8*)(As + (wm*64+f*16+col)*32 + rg*8);
      bfr[f] = *(const bf16x8*)(Bs + (wn*64+f*16+col)*32 + rg*8);
    }
    #pragma unroll
    for (int fm=0;fm<4;fm++)
      #pragma unroll
      for (int fn=0;fn<4;fn++)
        acc[fm][fn] = mfma16(af[fm], bfr[fn], acc[fm][fn]);
  }
  #pragma unroll
  for (int fm=0;fm<4;fm++){
    int mrow = m0 + wm*64 + fm*16 + rg*4;
    #pragma unroll
    for (int fn=0;fn<4;fn++){
      int gcol = n0 + wn*64 + fn*16 + col;
      float bv = bias ? bias[gcol] : 0.f;
      #pragma unroll
      for (int i=0;i<4;i++){
        float v = acc[fm][fn][i] + bv;
        int grow = mrow + i;
        if (MODE==0) ((float*)outp)[(size_t)grow*N + gcol] = v;
        else if (MODE==1) ((ushort*)outp)[(size_t)grow*N + gcol] = f2bf(v);
        else if (MODE==3) ((ushort*)outp)[(size_t)(grow>>4)*(16*2048) + gcol*16 + (grow&15)] = f2bf(v);
        else { if (grow < Mvalid){ int b = grow&15, t = grow>>4;
               ((float*)outp)[(size_t)b*T_*V_ + (size_t)(t+1)*V_ + gcol] = v; } }
      }
    }
  }
}

// ---------------- persistent bidirectional encoder: 16 WGs/dir x 512 thr (r17 + dual-acc) ----------------
__global__ __launch_bounds__(512) void k_enc_persist(
    const ushort* __restrict__ Xgf, const ushort* __restrict__ Xgb,
    const float* __restrict__ Whhf, const float* __restrict__ Whhb,
    ushort* __restrict__ enc, ushort* __restrict__ enct,
    uint* __restrict__ hbuf1, float* __restrict__ cbuf0,
    uint* __restrict__ hgf, uint* __restrict__ hgb){
  const int dir = blockIdx.x >> 4;
  const int wg  = blockIdx.x & 15;
  const ushort* Xg = dir ? Xgb : Xgf;
  const float* Whh = dir ? Whhb : Whhf;
  uint* hg = dir ? hgb : hgf;
  __shared__ __align__(16) ushort Wlds[128*512];   // 128 KiB, XOR-swizzled
  __shared__ __align__(16) ushort hls[16*512];     // 16 KiB staged h, XOR-swizzled
  int tid = threadIdx.x;
  for (int it=0; it<32; ++it){
    int r = it*4 + (tid>>7), ct = tid&127;
    int w_ = r>>4, jj=(r>>2)&3, g=r&3;
    int srow = g*H_ + wg*32 + w_*4 + jj;
    float4 v = *(const float4*)(Whh + (size_t)srow*H_ + ct*4);
    ushort4 o; o.x=f2bf(v.x); o.y=f2bf(v.y); o.z=f2bf(v.z); o.w=f2bf(v.w);
    int byte = (r*1024 + ct*8) ^ ((r&7)<<4);
    *(ushort4*)((char*)Wlds + byte) = o;
  }
  int w = tid>>6, lane = tid&63, colL = lane&15, rg = lane>>4;
  int gg = colL&3;
  float cst[4];
  #pragma unroll
  for (int i=0;i<4;i++) cst[i]=0.f;
  __syncthreads();
  for (int t=0;t<S_;++t){
    int pos = dir ? (S_-1-t) : t;
    const uint* hsrcU = hg + (t&1)*B_*H_;
    // tag-poll h_t: want tag == t (t=0: zeros, tag 0)
    uint uu[16];
    for(;;){
      #pragma unroll
      for (int k2=0;k2<2;k2++){
        int idx = tid + k2*512;
        const uint* p = hsrcU + (idx>>6)*H_ + (idx&63)*8;
        #pragma unroll
        for (int j=0;j<4;j++){
          ull v = ald64(p + j*2);
          uu[k2*8+j*2] = (uint)v; uu[k2*8+j*2+1] = (uint)(v>>32);
        }
      }
      bool ok = true;
      #pragma unroll
      for (int i2=0;i2<16;i2++) ok &= ((uu[i2]>>16) == (uint)t);
      if (ok) break;
      __builtin_amdgcn_s_sleep(1);
    }
    int colg = wg*128 + w*16 + colL;
    ushort4 xv = *(const ushort4*)(Xg + ((size_t)pos*2048 + colg)*16 + rg*4);
    f32x4 acc;
    acc[0]=bf2f(xv.x); acc[1]=bf2f(xv.y); acc[2]=bf2f(xv.z); acc[3]=bf2f(xv.w);
    f32x4 acc2 = {0.f,0.f,0.f,0.f};
    #pragma unroll
    for (int k2=0;k2<2;k2++){
      int idx = tid + k2*512;
      int byte = ((idx>>6)*1024 + (idx&63)*16) ^ (((idx>>6)&7)<<4);
      ushort tmp[8];
      #pragma unroll
      for (int j=0;j<8;j++) tmp[j] = (ushort)uu[k2*8+j];
      *(bf16x8*)((char*)hls + byte) = *(bf16x8*)tmp;
    }
    __syncthreads();
    int rowb = w*16 + colL;
    int base = rowb*1024 + rg*16, xm = (rowb&7)<<4;
    int hbase = colL*1024 + rg*16, hxm = (colL&7)<<4;
    #pragma unroll
    for (int kt=0;kt<8;kt++){
      bf16x8 a0 = *(const bf16x8*)((const char*)hls + ((hbase + kt*64) ^ hxm));
      bf16x8 b0 = *(const bf16x8*)((const char*)Wlds + ((base + kt*64) ^ xm));
      acc = mfma16(a0, b0, acc);
      bf16x8 a1 = *(const bf16x8*)((const char*)hls + ((hbase + (kt+8)*64) ^ hxm));
      bf16x8 b1 = *(const bf16x8*)((const char*)Wlds + ((base + (kt+8)*64) ^ xm));
      acc2 = mfma16(a1, b1, acc2);
    }
    #pragma unroll
    for (int i=0;i<4;i++) acc[i] += acc2[i];
    uint* hdstU = hg + ((t+1)&1)*B_*H_;
    #pragma unroll
    for (int i=0;i<4;i++){
      float v0 = acc[i];
      float v1 = __shfl_xor(v0, 1);
      float v2 = __shfl_xor(v0, 2);
      float v3 = __shfl_xor(v1, 2);
      float zi = gg==0?v0: gg==1?v1: gg==2?v2: v3;
      float zf = (gg^1)==0?v0: (gg^1)==1?v1: (gg^1)==2?v2: v3;
      float zg = (gg^2)==0?v0: (gg^2)==1?v1: (gg^2)==2?v2: v3;
      float zo = (gg^3)==0?v0: (gg^3)==1?v1: (gg^3)==2?v2: v3;
      float cc = fsig(zf)*cst[i] + fsig(zi)*ftanh(zg);
      cst[i] = cc;
      float h = fsig(zo)*ftanh(cc);
      if (gg==0){
        int j = wg*32 + w*4 + (colL>>2);
        int b = rg*4+i;
        ushort hb = f2bf(h);
        enc[((size_t)b*S_ + pos)*H2_ + dir*H_ + j] = hb;
        enct[((size_t)b*H2_ + dir*H_ + j)*S_ + pos] = hb;
        astu(&hdstU[b*H_ + j], (uint)hb | ((uint)(t+1)<<16));
        if (t==S_-1){
          hbuf1[b*H2_ + dir*H_ + j] = (uint)hb;  // decoder h0, tag 0
          cbuf0[b*H2_ + dir*H_ + j] = cc;        // decoder c0
        }
      }
    }
    __syncthreads();   // protect hls reuse across steps
  }
}

// ---------------- persistent decoder: 256 WGs x 512 threads, all-tag sync (r17) ----------------
__global__ __launch_bounds__(512) void k_dec(
    const float* __restrict__ P, const ushort* __restrict__ WaH,
    const ushort* __restrict__ Wd, const float* __restrict__ bsd,
    const ushort* __restrict__ enct, const ushort* __restrict__ DXb,
    const float* __restrict__ cbuf0, uint* __restrict__ hU,
    uint* __restrict__ ctxU, ull* __restrict__ qU,
    ull* __restrict__ sU, ushort* __restrict__ hsd){
  __shared__ __align__(16) ushort AB[16*ASTR];   // 74KB phase-D xi stage
  __shared__ __align__(16) float pr[8*256];
  __shared__ float redz[256];
  __shared__ float qls[1024];
  __shared__ float wls[512];
  __shared__ float part[512];
  __shared__ float red[16];
  __shared__ float cst[64];
  int wgid = blockIdx.x, tid = threadIdx.x;
  int w = tid>>6, lane = tid&63, colL = lane&15, rg = lane>>4;
  int b = wgid>>4, wc = wgid&15;
  if (tid < 64){
    int jj = tid>>4, b4 = tid&15;
    cst[tid] = cbuf0[b4*H2_ + wgid*4 + jj];
  }
  for (int st=0; st<DSTEPS; ++st){
    const uint* hprevU = hU + ((st+1)&1)*B_*H2_;
    uint* cslot = ctxU + (st&1)*B_*H2_;
    const uint wantH = (uint)st;
    const uint wantT = (uint)(st+1);   // q / scores / ctx / h-out tags
    // ---- phase A: q = h_{t-1} @ WaH^T (WGs 64..127); h tag-poll, q tagged out ----
    if (wgid >= 64 && wgid < 128){
      int n0 = (wgid-64)*16;
      const uint* hp = hprevU + colL*H2_ + w*128 + rg*8;
      uint uu[32];
      for(;;){
        #pragma unroll
        for (int kt=0;kt<4;kt++)
          #pragma unroll
          for (int j=0;j<4;j++){
            ull v = ald64(hp + kt*32 + j*2);
            uu[kt*8+j*2] = (uint)v; uu[kt*8+j*2+1] = (uint)(v>>32);
          }
        bool ok = true;
        #pragma unroll
        for (int i2=0;i2<32;i2++) ok &= ((uu[i2]>>16) == wantH);
        if (ok) break;
        __builtin_amdgcn_s_sleep(1);
      }
      f32x4 acc = {0.f,0.f,0.f,0.f};
      const ushort* Bp = WaH + (size_t)(n0+colL)*H2_ + w*128 + rg*8;
      #pragma unroll
      for (int kt=0;kt<4;kt++){
        ushort tmp[8];
        #pragma unroll
        for (int j=0;j<8;j++) tmp[j] = (ushort)uu[kt*8+j];
        acc = mfma16(*(bf16x8*)tmp, *(const bf16x8*)(Bp + kt*32), acc);
      }
      *(f32x4*)&pr[w*256 + lane*4] = acc;
      __syncthreads();
      if (tid < 256){
        float s = pr[tid];
        #pragma unroll
        for (int w8=1;w8<8;w8++) s += pr[w8*256 + tid];
        int l = tid>>2, i = tid&3;
        ast64(&qU[(size_t)((l>>4)*4 + i)*H2_ + n0 + (l&15)], pack2f(s, wantT));
      }
    }
    // ---- phase B: poll q data (in-band), scores = sum_k tanh(P + q) ----
    {
      const ull* qp = qU + (size_t)b*H2_;
      ull v0, v1;
      for(;;){
        v0 = ald64(qp + tid*2);
        v1 = ald64(qp + tid*2 + 1);
        if (tagok2(v0, wantT) && tagok2(v1, wantT)) break;
        __builtin_amdgcn_s_sleep(1);
      }
      qls[tid*2]   = unpack2f(v0);
      qls[tid*2+1] = unpack2f(v1);
      __syncthreads();
      f32x4 qv[4];
      #pragma unroll
      for (int u=0;u<4;u++) qv[u] = *(const f32x4*)&qls[lane*16 + u*4];
      int rbase = b*S_ + wc*32 + w*4;
      #pragma unroll
      for (int rr=0;rr<4;rr++){
        int r = rbase + rr;
        const float4* Pr = (const float4*)(P + (size_t)r*H2_) + lane*4;
        float s = 0.f;
        #pragma unroll
        for (int u=0;u<4;u++){
          float4 pv = Pr[u];
          s += ftanh(pv.x+qv[u][0])+ftanh(pv.y+qv[u][1])+ftanh(pv.z+qv[u][2])+ftanh(pv.w+qv[u][3]);
        }
        #pragma unroll
        for (int o=32;o;o>>=1) s += __shfl_xor(s,o);
        if (lane==0) ast64(&sU[r], pack2f(s, wantT));
      }
    }
    __syncthreads();
    // ---- phase C: poll scores data (in-band), softmax + ctx; ctx TAGGED ----
    {
      ull sv;
      const ull* sp = sU + (size_t)b*S_ + tid;
      for(;;){
        sv = ald64(sp);
        if (tagok2(sv, wantT)) break;
        __builtin_amdgcn_s_sleep(1);
      }
      float sc = unpack2f(sv);
      float m = sc;
      #pragma unroll
      for (int o=32;o;o>>=1) m = fmaxf(m, __shfl_xor(m,o));
      if (lane==0) red[w] = m;
      __syncthreads();
      m = red[0];
      #pragma unroll
      for (int k2=1;k2<8;k2++) m = fmaxf(m, red[k2]);
      float e = __builtin_amdgcn_exp2f((sc - m)*LOG2E);
      float ss = e;
      #pragma unroll
      for (int o=32;o;o>>=1) ss += __shfl_xor(ss,o);
      if (lane==0) red[8+w] = ss;
      __syncthreads();
      float tot = red[8];
      #pragma unroll
      for (int k2=9;k2<16;k2++) tot += red[k2];
      wls[tid] = e * __builtin_amdgcn_rcpf(tot);
      __syncthreads();
      int c = wc*64 + (tid&63), sseg = tid>>6;
      const ushort* ep = enct + ((size_t)b*H2_ + c)*S_ + sseg*64;
      float a = 0.f;
      #pragma unroll
      for (int u=0;u<8;u++){
        bf16x8 ev = *(const bf16x8*)(ep + u*8);
        #pragma unroll
        for (int j=0;j<8;j++) a += wls[sseg*64 + u*8 + j] * bf2f((ushort)ev[j]);
      }
      part[tid] = a;
      __syncthreads();
      if (tid < 64){
        float s = part[tid];
        #pragma unroll
        for (int g2=1;g2<8;g2++) s += part[g2*64 + tid];
        astu(&cslot[b*H2_ + wc*64 + tid], (uint)f2bf(s) | (wantT<<16));
      }
    }
    // ---- phase D: merged ctx+h tag-poll, stage, gates MFMA (k-split 8x288), cell ----
    {
      { int b3 = tid>>5, seg = tid&31;
        *(bf16x8*)&AB[b3*ASTR + seg*8] = *(const bf16x8*)(DXb + (size_t)(st*16+b3)*E_ + seg*8); }
      uint uc[32], uh[32];
      for(;;){
        #pragma unroll
        for (int k2=0;k2<4;k2++){
          int idx = tid + k2*512;
          const uint* pc = cslot  + (idx>>7)*H2_ + (idx&127)*8;
          const uint* ph = hprevU + (idx>>7)*H2_ + (idx&127)*8;
          #pragma unroll
          for (int j=0;j<4;j++){
            ull vc = ald64(pc + j*2);
            ull vh = ald64(ph + j*2);
            uc[k2*8+j*2] = (uint)vc; uc[k2*8+j*2+1] = (uint)(vc>>32);
            uh[k2*8+j*2] = (uint)vh; uh[k2*8+j*2+1] = (uint)(vh>>32);
          }
        }
        bool ok = true;
        #pragma unroll
        for (int i2=0;i2<32;i2++) ok &= ((uc[i2]>>16) == wantT) && ((uh[i2]>>16) == wantH);
        if (ok) break;
        __builtin_amdgcn_s_sleep(1);
      }
      #pragma unroll
      for (int k2=0;k2<4;k2++){
        int idx = tid + k2*512;
        ushort tc[8], th[8];
        #pragma unroll
        for (int j=0;j<8;j++){ tc[j] = (ushort)uc[k2*8+j]; th[j] = (ushort)uh[k2*8+j]; }
        *(bf16x8*)&AB[(idx>>7)*ASTR + 256  + (idx&127)*8] = *(bf16x8*)tc;
        *(bf16x8*)&AB[(idx>>7)*ASTR + 1280 + (idx&127)*8] = *(bf16x8*)th;
      }
      __syncthreads();
      int row0 = wgid*16;
      f32x4 acc = {0.f,0.f,0.f,0.f};
      const ushort* Bp = Wd + (size_t)(row0+colL)*KXI_ + w*288 + rg*8;
      const ushort* Apb = &AB[colL*ASTR + w*288 + rg*8];
      #pragma unroll
      for (int kt=0;kt<9;kt++)
        acc = mfma16(*(const bf16x8*)(Apb + kt*32), *(const bf16x8*)(Bp + kt*32), acc);
      *(f32x4*)&pr[w*256 + lane*4] = acc;
      __syncthreads();
      if (tid < 256){
        float s = bsd[row0 + ((tid>>2)&15)];
        #pragma unroll
        for (int w8=0;w8<8;w8++) s += pr[w8*256 + tid];
        redz[tid] = s;
      }
      __syncthreads();
      if (tid < 64){
        int jj = tid>>4, b4 = tid&15, rgc = b4>>2, ic = b4&3;
        float zi = redz[((jj*4+0) + 16*rgc)*4 + ic];
        float zf = redz[((jj*4+1) + 16*rgc)*4 + ic];
        float zg = redz[((jj*4+2) + 16*rgc)*4 + ic];
        float zo = redz[((jj*4+3) + 16*rgc)*4 + ic];
        float cc2 = fsig(zf)*cst[tid] + fsig(zi)*ftanh(zg);
        cst[tid] = cc2;
        float h = fsig(zo)*ftanh(cc2);
        ushort hb = f2bf(h);
        int j = wgid*4 + jj;
        astu(&hU[(st&1)*B_*H2_ + b4*H2_ + j], (uint)hb | (wantT<<16));
        hsd[((size_t)st*B_ + b4)*H2_ + j] = hb;
      }
      __syncthreads();
    }
  }
}

extern "C" void kernel_launch(void* const* d_in, const int* in_sizes, int n_in,
                              void* d_out, int out_size, void* d_ws, size_t ws_size,
                              hipStream_t stream) {
  const int* src   = (const int*)d_in[0];
  const int* tgt   = (const int*)d_in[1];
  const float* emb   = (const float*)d_in[2];
  const float* Wih_f = (const float*)d_in[3];
  const float* Whh_f = (const float*)d_in[4];
  const float* bih_f = (const float*)d_in[5];
  const float* bhh_f = (const float*)d_in[6];
  const float* Wih_b = (const float*)d_in[7];
  const float* Whh_b = (const float*)d_in[8];
  const float* bih_b = (const float*)d_in[9];
  const float* bhh_b = (const float*)d_in[10];
  const float* Wih_d = (const float*)d_in[11];
  const float* Whh_d = (const float*)d_in[12];
  const float* bih_d = (const float*)d_in[13];
  const float* bhh_d = (const float*)d_in[14];
  const float* Wa    = (const float*)d_in[15];
  const float* ba    = (const float*)d_in[16];
  const float* Wo    = (const float*)d_in[17];
  const float* bo    = (const float*)d_in[18];
  float* out = (float*)d_out;
  (void)in_sizes; (void)n_in; (void)out_size; (void)ws_size;

  char* ws = (char*)d_ws;
  size_t off = 0;
  auto alloc = [&](size_t bytes)->char*{ char* p = ws + off; off += (bytes + 255) & ~(size_t)255; return p; };
  ushort* Xb     = (ushort*)alloc((size_t)S_*B_*E_*2);
  ushort* DXb    = (ushort*)alloc((size_t)DSTEPS*B_*E_*2);
  ushort* Wihf_p = (ushort*)alloc((size_t)G4_*E_*2);
  ushort* Wihb_p = (ushort*)alloc((size_t)G4_*E_*2);
  float*  bsf    = (float*)alloc(G4_*4);
  float*  bsb    = (float*)alloc(G4_*4);
  ushort* ENC    = (ushort*)alloc((size_t)B_*S_*H2_*2);
  ushort* ENCT   = (ushort*)alloc((size_t)B_*S_*H2_*2);
  ushort* WaH    = (ushort*)alloc((size_t)H2_*H2_*2);
  ushort* WaE    = (ushort*)alloc((size_t)H2_*H2_*2);
  ushort* Wd     = (ushort*)alloc((size_t)D4_*KXI_*2);
  float*  bsd    = (float*)alloc(D4_*4);
  ushort* WoB    = (ushort*)alloc((size_t)V_*H2_*2);
  float*  cbuf0  = (float*)alloc(B_*H2_*4);
  uint*   hU     = (uint*)alloc((size_t)2*B_*H2_*4);   // tagged h, 2 slots
  uint*   ctxU   = (uint*)alloc((size_t)2*B_*H2_*4);   // tagged ctx, 2 slots
  ull*    qU     = (ull*)alloc((size_t)B_*H2_*8);      // tagged hi/lo q
  ull*    sU     = (ull*)alloc((size_t)B_*S_*8);       // tagged hi/lo scores
  ushort* hsd    = (ushort*)alloc((size_t)MD*H2_*2);
  uint*   hgf    = (uint*)alloc((size_t)2*B_*H_*4);    // tagged encoder h (fwd)
  uint*   hgb    = (uint*)alloc((size_t)2*B_*H_*4);    // tagged encoder h (bwd)
  uint*   flags  = (uint*)alloc(4096);
  char*   big    = alloc((size_t)2*S_*B_*G4_*2);   // Xgf+Xgb; later aliased by P (f32)
  ushort* Xgf = (ushort*)big;
  ushort* Xgb = (ushort*)(big + (size_t)S_*B_*G4_*2);
  float*  P   = (float*)big;

  // ---- setup ----
  k_init<<<dim3(128), dim3(256), 0, stream>>>(flags, hgf, hgb, hU, ctxU, (uint*)qU, (uint*)sU);
  k_embed<<<dim3(S_*B_ + DSTEPS*B_), dim3(E_), 0, stream>>>(src, tgt, emb, Xb, DXb);
  k_cvt_encw<<<dim3(G4_), dim3(256), 0, stream>>>(Wih_f, Wihf_p);
  k_cvt_encw<<<dim3(G4_), dim3(256), 0, stream>>>(Wih_b, Wihb_p);
  k_bias_encp<<<dim3(8), dim3(256), 0, stream>>>(bih_f, bhh_f, bsf);
  k_bias_encp<<<dim3(8), dim3(256), 0, stream>>>(bih_b, bhh_b, bsb);
  k_cvt_strided<<<dim3(H2_), dim3(256), 0, stream>>>(Wa, WaH, H2_, 2*H2_, 0,   H2_, 0);
  k_cvt_strided<<<dim3(H2_), dim3(256), 0, stream>>>(Wa, WaE, H2_, 2*H2_, H2_, H2_, 0);
  k_cvt_decw<<<dim3(D4_), dim3(256), 0, stream>>>(Wih_d, Whh_d, Wd);
  k_bias_decp<<<dim3(16), dim3(256), 0, stream>>>(bih_d, bhh_d, bsd);
  k_cvt_strided<<<dim3(V_),  dim3(256), 0, stream>>>(Wo, WoB, H2_, H2_, 0, H2_, 0);

  // ---- encoder input-gate pre-GEMMs -> [s][col][b] layout (MODE 3) ----
  gemm128<3><<<dim3(G4_/128, (S_*B_)/128), dim3(256), 0, stream>>>(Xb, Wihf_p, bsf, Xgf, S_*B_, G4_, E_, 0);
  gemm128<3><<<dim3(G4_/128, (S_*B_)/128), dim3(256), 0, stream>>>(Xb, Wihb_p, bsb, Xgb, S_*B_, G4_, E_, 0);

  // ---- persistent bidirectional encoder (32 WGs: 16/dir), tag-synced ----
  k_enc_persist<<<dim3(32), dim3(512), 0, stream>>>(Xgf, Xgb, Whh_f, Whh_b, ENC, ENCT,
                                                    hU + B_*H2_, cbuf0, hgf, hgb);

  // ---- enc_proj = enc_out @ Wa_e^T + ba ----
  gemm128<0><<<dim3(H2_/128, (B_*S_)/128), dim3(256), 0, stream>>>(ENC, WaE, ba, P, B_*S_, H2_, H2_, 0);
  k_zero_t0<<<dim3((B_*V_+255)/256), dim3(256), 0, stream>>>(out);

  // ---- persistent decoder (256 WGs x 512 threads), all-tag sync ----
  k_dec<<<dim3(NWG_DEC), dim3(512), 0, stream>>>(P, WaH, Wd, bsd, ENCT, DXb, cbuf0, hU,
                                                 ctxU, qU, sU, hsd);

  // ---- final projection ----
  gemm128<2><<<dim3(V_/128, MD/128), dim3(256), 0, stream>>>(hsd, WoB, bo, out, MD, V_, H2_, DSTEPS*B_);
}